// Round 4
// baseline (605.972 us; speedup 1.0000x reference)
//
#include <hip/hip_runtime.h>
#include <hip/hip_bf16.h>

// B=2, T=2048, C=1024, H=16, D=64, M=B*T=4096
// All GEMMs: exact integer math via bf16 MFMA (ints <= 2^24 exact in fp32 accum).

typedef __attribute__((ext_vector_type(8))) short bf16x8;
typedef __attribute__((ext_vector_type(4))) float f32x4;

__device__ __forceinline__ f32x4 mfma16(bf16x8 a, bf16x8 b, f32x4 c) {
    return __builtin_amdgcn_mfma_f32_16x16x32_bf16(a, b, c, 0, 0, 0);
}

__device__ __forceinline__ unsigned short f2bf(float f) {
    unsigned int u = __float_as_uint(f);
    unsigned int r = (u + 0x7fffu + ((u >> 16) & 1u)) >> 16;
    return (unsigned short)r;
}

__device__ __forceinline__ unsigned int cvtpk_bf16(float lo, float hi) {
    unsigned int r;
    asm("v_cvt_pk_bf16_f32 %0, %1, %2" : "=v"(r) : "v"(lo), "v"(hi));
    return r;
}

__device__ __forceinline__ float wredsum(float v) {
#pragma unroll
    for (int o = 32; o > 0; o >>= 1) v += __shfl_xor(v, o);
    return v;
}
__device__ __forceinline__ float wredmax(float v) {
#pragma unroll
    for (int o = 32; o > 0; o >>= 1) v = fmaxf(v, __shfl_xor(v, o));
    return v;
}

// ---------------- weight absmean partials (deterministic two-pass) ----------
__global__ __launch_bounds__(256) void wabssum(const float* __restrict__ w0, const float* __restrict__ w1,
                                               const float* __restrict__ w2, const float* __restrict__ w3,
                                               float* __restrict__ part) {
    int widx = blockIdx.x >> 5, b = blockIdx.x & 31;
    const float* w = (widx == 0) ? w0 : (widx == 1) ? w1 : (widx == 2) ? w2 : w3;
    const float4* w4 = (const float4*)w;
    int tid = threadIdx.x;
    float s = 0.f;
    int base = b * 8192 + tid;  // float4 units; 32 blocks * 8192 = 262144 = 1M floats
#pragma unroll
    for (int i = 0; i < 32; ++i) {
        float4 v = w4[base + i * 256];
        s += fabsf(v.x) + fabsf(v.y) + fabsf(v.z) + fabsf(v.w);
    }
    s = wredsum(s);
    __shared__ float red[4];
    int wid = tid >> 6, lid = tid & 63;
    if (lid == 0) red[wid] = s;
    __syncthreads();
    if (tid == 0) part[blockIdx.x] = red[0] + red[1] + red[2] + red[3];
}

// ---------------- ternary weight quant -> bf16 {-1,0,1} ---------------------
__global__ __launch_bounds__(256) void wquant(const float* __restrict__ w0, const float* __restrict__ w1,
                                              const float* __restrict__ w2, const float* __restrict__ w3,
                                              const float* __restrict__ part, unsigned short* __restrict__ wbf) {
    int widx = blockIdx.x >> 6, b = blockIdx.x & 63;
    const float* w = (widx == 0) ? w0 : (widx == 1) ? w1 : (widx == 2) ? w2 : w3;
    float s = 0.f;
#pragma unroll
    for (int i = 0; i < 32; ++i) s += part[widx * 32 + i];
    s = fmaxf(s * (1.f / 1048576.f), 1e-5f);
    float inv = 1.f / s;
    const float4* w4 = (const float4*)w;
    unsigned short* dst = wbf + (size_t)widx * 1048576;
    int tid = threadIdx.x;
#pragma unroll
    for (int it = 0; it < 16; ++it) {
        int i4 = b * 4096 + it * 256 + tid;
        float4 v = w4[i4];
        float q0 = fminf(fmaxf(rintf(v.x * inv), -1.f), 1.f);
        float q1 = fminf(fmaxf(rintf(v.y * inv), -1.f), 1.f);
        float q2 = fminf(fmaxf(rintf(v.z * inv), -1.f), 1.f);
        float q3 = fminf(fmaxf(rintf(v.w * inv), -1.f), 1.f);
        ((ushort4*)dst)[i4] = make_ushort4(f2bf(q0), f2bf(q1), f2bf(q2), f2bf(q3));
    }
}

// ------------- fused rmsnorm + per-token absmax quant (NP planes) -----------
template <int NP>
__global__ __launch_bounds__(256) void actquant(const float* __restrict__ x, const float* __restrict__ g0,
                                                const float* __restrict__ g1, const float* __restrict__ g2,
                                                unsigned short* __restrict__ aq, float* __restrict__ ascale) {
    int m = blockIdx.x, tid = threadIdx.x;
    int wid = tid >> 6, lid = tid & 63;
    __shared__ float red[4];
    float4 xv = ((const float4*)(x + (size_t)m * 1024))[tid];
    float ss = xv.x * xv.x + xv.y * xv.y + xv.z * xv.z + xv.w * xv.w;
    ss = wredsum(ss);
    if (lid == 0) red[wid] = ss;
    __syncthreads();
    float rstd = rsqrtf((red[0] + red[1] + red[2] + red[3]) * (1.f / 1024.f) + 1e-6f);
    const float* gs[3] = {g0, g1, g2};
#pragma unroll
    for (int p = 0; p < NP; ++p) {
        float4 gv = ((const float4*)gs[p])[tid];
        float a0 = xv.x * gv.x * rstd, a1 = xv.y * gv.y * rstd;
        float a2 = xv.z * gv.z * rstd, a3 = xv.w * gv.w * rstd;
        float am = fmaxf(fmaxf(fabsf(a0), fabsf(a1)), fmaxf(fabsf(a2), fabsf(a3)));
        am = wredmax(am);
        __syncthreads();  // protect red from previous use
        if (lid == 0) red[wid] = am;
        __syncthreads();
        float rm = fmaxf(fmaxf(red[0], red[1]), fmaxf(red[2], red[3]));
        float scale = 127.f / fmaxf(rm, 1e-5f);
        float q0 = fminf(fmaxf(rintf(a0 * scale), -128.f), 127.f);
        float q1 = fminf(fmaxf(rintf(a1 * scale), -128.f), 127.f);
        float q2 = fminf(fmaxf(rintf(a2 * scale), -128.f), 127.f);
        float q3 = fminf(fmaxf(rintf(a3 * scale), -128.f), 127.f);
        ((ushort4*)(aq + (size_t)p * 4194304 + (size_t)m * 1024))[tid] =
            make_ushort4(f2bf(q0), f2bf(q1), f2bf(q2), f2bf(q3));
        if (tid == 0) ascale[p * 4096 + m] = scale;
    }
}

// ---------------- bf16 integer GEMM: [4096,1024] x [1024,1024]^T ------------
// MODE 0: out bf16 [B,H,T,D]; MODE 1: out bf16 [BH,D,T] (V transposed); MODE 2: out f32 [M,N]
template <int MODE>
__global__ __launch_bounds__(256) void gemm_bf16(const unsigned short* __restrict__ A,
                                                 const float* __restrict__ asc,
                                                 const unsigned short* __restrict__ W,
                                                 const float* __restrict__ part, void* __restrict__ outp) {
    __shared__ alignas(16) unsigned short As[64][72];  // pad 72 -> 2-way-max bank alias
    __shared__ alignas(16) unsigned short Bs[64][72];
    int bid = blockIdx.x;
    int bm = bid & 63, bn = bid >> 6;
    int tid = threadIdx.x;
    int w = tid >> 6, l = tid & 63;
    int wr = w >> 1, wc = w & 1;
    int lr = l & 15, lh = l >> 4;
    float s = 0.f;
#pragma unroll
    for (int i = 0; i < 32; ++i) s += part[i];
    float s_w = fmaxf(s * (1.f / 1048576.f), 1e-5f);

    f32x4 acc[2][2] = {};
    int strow = tid >> 3;          // 0..31
    int stcol = (tid & 7) * 8;     // short offset, 16B chunks
    const unsigned short* Abase = A + (size_t)(bm * 64) * 1024;
    const unsigned short* Wbase = W + (size_t)(bn * 64) * 1024;

    for (int kt = 0; kt < 16; ++kt) {
        int k0 = kt * 64;
        __syncthreads();
#pragma unroll
        for (int ps = 0; ps < 2; ++ps) {
            int row = ps * 32 + strow;
            *(int4*)&As[row][stcol] = *(const int4*)&Abase[(size_t)row * 1024 + k0 + stcol];
            *(int4*)&Bs[row][stcol] = *(const int4*)&Wbase[(size_t)row * 1024 + k0 + stcol];
        }
        __syncthreads();
#pragma unroll
        for (int ks = 0; ks < 2; ++ks) {
            int kb = ks * 32 + lh * 8;
            bf16x8 af[2], bfr[2];
            af[0] = *(const bf16x8*)&As[wr * 32 + lr][kb];
            af[1] = *(const bf16x8*)&As[wr * 32 + 16 + lr][kb];
            bfr[0] = *(const bf16x8*)&Bs[wc * 32 + lr][kb];
            bfr[1] = *(const bf16x8*)&Bs[wc * 32 + 16 + lr][kb];
#pragma unroll
            for (int mi = 0; mi < 2; ++mi)
#pragma unroll
                for (int ni = 0; ni < 2; ++ni) acc[mi][ni] = mfma16(af[mi], bfr[ni], acc[mi][ni]);
        }
    }
#pragma unroll
    for (int mi = 0; mi < 2; ++mi) {
        int mbase = bm * 64 + wr * 32 + mi * 16 + lh * 4;
#pragma unroll
        for (int ni = 0; ni < 2; ++ni) {
            int n = bn * 64 + wc * 32 + ni * 16 + lr;
            if (MODE == 1) {
                int b = mbase >> 11, t0 = mbase & 2047;
                int h = n >> 6, d = n & 63;
                ushort4 st;
                st.x = f2bf(acc[mi][ni][0] * s_w / asc[mbase + 0]);
                st.y = f2bf(acc[mi][ni][1] * s_w / asc[mbase + 1]);
                st.z = f2bf(acc[mi][ni][2] * s_w / asc[mbase + 2]);
                st.w = f2bf(acc[mi][ni][3] * s_w / asc[mbase + 3]);
                *(ushort4*)&((unsigned short*)outp)[(size_t)(b * 16 + h) * 131072 + (size_t)d * 2048 + t0] = st;
            } else {
#pragma unroll
                for (int i = 0; i < 4; ++i) {
                    int m = mbase + i;
                    float val = acc[mi][ni][i] * s_w / asc[m];
                    if (MODE == 0) {
                        int b = m >> 11, t = m & 2047, h = n >> 6, d = n & 63;
                        ((unsigned short*)outp)[(size_t)(b * 16 + h) * 131072 + (size_t)t * 64 + d] = f2bf(val);
                    } else {
                        ((float*)outp)[(size_t)m * 1024 + n] = val;
                    }
                }
            }
        }
    }
}

// ---------------- flash attention (causal, 16 heads, D=64) ------------------
// 4 waves per block share one 64-row chunk; all 4 waves issue IDENTICAL K/V
// addresses (lane-dependent only) -> L1 serves 3 of 4 (4x less L2 traffic).
// bh = blk&31 co-locates each head's blocks on one XCD (round-robin %8) so
// K/V (512KB/bh, 4 bh/XCD = 2MB) stays L2-resident. Heavy chunks first.
// Swapped QK^T: S^T = mfma(K,Q); softmax in-register per lane's q-row.
__global__ __launch_bounds__(256) void attn(const unsigned short* __restrict__ qb,
                                            const unsigned short* __restrict__ kb,
                                            const unsigned short* __restrict__ vt, float* __restrict__ y) {
    int blk = blockIdx.x;
    int bh = blk & 31;
    int cb = 63 - (blk >> 5);  // 64-row chunk, heaviest first
    int w = threadIdx.x >> 6;
    int l = threadIdx.x & 63;
    int q0 = (cb << 6) + (w << 4);  // this wave's 16 rows
    int lr = l & 15, lh = l >> 4;
    const unsigned short* qbase = qb + (size_t)bh * 131072;
    const unsigned short* kbase = kb + (size_t)bh * 131072;
    const unsigned short* vbase = vt + (size_t)bh * 131072;

    bf16x8 qf0 = *(const bf16x8*)&qbase[(size_t)(q0 + lr) * 64 + lh * 8];
    bf16x8 qf1 = *(const bf16x8*)&qbase[(size_t)(q0 + lr) * 64 + 32 + lh * 8];

    f32x4 o0 = {}, o1 = {}, o2 = {}, o3 = {};
    float ninf = -__builtin_inff();
    float mreg = ninf;  // running max for q-row = q0+lr
    float lreg = 0.f;   // running sum for q-row = q0+lr
    __shared__ alignas(16) unsigned short plds[4][16][40];  // per-wave private

    int qrow = q0 + lr;
    int ntiles = (q0 + 47) >> 5;

    auto LOADK = [&](int kv0, bf16x8* k) {
        k[0] = *(const bf16x8*)&kbase[(size_t)(kv0 + lr) * 64 + lh * 8];
        k[1] = *(const bf16x8*)&kbase[(size_t)(kv0 + lr) * 64 + 32 + lh * 8];
        k[2] = *(const bf16x8*)&kbase[(size_t)(kv0 + 16 + lr) * 64 + lh * 8];
        k[3] = *(const bf16x8*)&kbase[(size_t)(kv0 + 16 + lr) * 64 + 32 + lh * 8];
    };
    auto LOADV = [&](int kv0, bf16x8* v) {
        v[0] = *(const bf16x8*)&vbase[(size_t)(lr)*2048 + kv0 + lh * 8];
        v[1] = *(const bf16x8*)&vbase[(size_t)(16 + lr) * 2048 + kv0 + lh * 8];
        v[2] = *(const bf16x8*)&vbase[(size_t)(32 + lr) * 2048 + kv0 + lh * 8];
        v[3] = *(const bf16x8*)&vbase[(size_t)(48 + lr) * 2048 + kv0 + lh * 8];
    };
    auto PROCESS = [&](int t, bf16x8* k, bf16x8* v) {
        int kv0 = t << 5;
        f32x4 s0 = {}, s1 = {};
        s0 = mfma16(k[0], qf0, s0);
        s0 = mfma16(k[1], qf1, s0);
        s1 = mfma16(k[2], qf0, s1);
        s1 = mfma16(k[3], qf1, s1);
        // s0[r] = S[q0+lr][kv0 + lh*4 + r], s1[r] = S[q0+lr][kv0 + 16 + lh*4 + r]
        float p[8];
#pragma unroll
        for (int r = 0; r < 4; ++r) {
            p[r]     = (kv0 + lh * 4 + r <= qrow)      ? s0[r] * 0.125f : ninf;
            p[r + 4] = (kv0 + 16 + lh * 4 + r <= qrow) ? s1[r] * 0.125f : ninf;
        }
        float tmax = fmaxf(fmaxf(fmaxf(p[0], p[1]), fmaxf(p[2], p[3])),
                           fmaxf(fmaxf(p[4], p[5]), fmaxf(p[6], p[7])));
        tmax = fmaxf(tmax, __shfl_xor(tmax, 16));
        tmax = fmaxf(tmax, __shfl_xor(tmax, 32));
        float mn = fmaxf(mreg, tmax);
        float cc = __expf(mreg - mn);
        float ps[8];
#pragma unroll
        for (int r = 0; r < 8; ++r) ps[r] = __expf(p[r] - mn);
        float sum = ((ps[0] + ps[1]) + (ps[2] + ps[3])) + ((ps[4] + ps[5]) + (ps[6] + ps[7]));
        sum += __shfl_xor(sum, 16);
        sum += __shfl_xor(sum, 32);
        lreg = lreg * cc + sum;
        mreg = mn;
        // pack + store P^T transpose via LDS: plds[w][q=lr][kv_rel]
        uint2 wlo, whi;
        wlo.x = cvtpk_bf16(ps[0], ps[1]);
        wlo.y = cvtpk_bf16(ps[2], ps[3]);
        whi.x = cvtpk_bf16(ps[4], ps[5]);
        whi.y = cvtpk_bf16(ps[6], ps[7]);
        *(uint2*)&plds[w][lr][lh * 4] = wlo;
        *(uint2*)&plds[w][lr][16 + lh * 4] = whi;
        // rescale O
#pragma unroll
        for (int r = 0; r < 4; ++r) {
            o0[r] *= cc; o1[r] *= cc; o2[r] *= cc; o3[r] *= cc;
        }
        bf16x8 pf = *(const bf16x8*)&plds[w][lr][lh * 8];
        o0 = mfma16(v[0], pf, o0);
        o1 = mfma16(v[1], pf, o1);
        o2 = mfma16(v[2], pf, o2);
        o3 = mfma16(v[3], pf, o3);
    };

    bf16x8 kA[4], vA[4], kB[4], vB[4];
    LOADK(0, kA);
    LOADV(0, vA);
    int t = 0;
    while (true) {
        if (t + 1 < ntiles) { LOADK((t + 1) << 5, kB); LOADV((t + 1) << 5, vB); }
        PROCESS(t, kA, vA);
        if (++t >= ntiles) break;
        if (t + 1 < ntiles) { LOADK((t + 1) << 5, kA); LOADV((t + 1) << 5, vA); }
        PROCESS(t, kB, vB);
        if (++t >= ntiles) break;
    }

    int b = bh >> 4, h = bh & 15;
    float invl = 1.f / lreg;
    float* yr = y + (size_t)(b * 2048 + qrow) * 1024 + h * 64;
    // o_di[r] = O[q=lr][d = di*16 + lh*4 + r]
    float4 st;
    st.x = o0[0] * invl; st.y = o0[1] * invl; st.z = o0[2] * invl; st.w = o0[3] * invl;
    *(float4*)&yr[lh * 4] = st;
    st.x = o1[0] * invl; st.y = o1[1] * invl; st.z = o1[2] * invl; st.w = o1[3] * invl;
    *(float4*)&yr[16 + lh * 4] = st;
    st.x = o2[0] * invl; st.y = o2[1] * invl; st.z = o2[2] * invl; st.w = o2[3] * invl;
    *(float4*)&yr[32 + lh * 4] = st;
    st.x = o3[0] * invl; st.y = o3[1] * invl; st.z = o3[2] * invl; st.w = o3[3] * invl;
    *(float4*)&yr[48 + lh * 4] = st;
}

extern "C" void kernel_launch(void* const* d_in, const int* in_sizes, int n_in,
                              void* d_out, int out_size, void* d_ws, size_t ws_size,
                              hipStream_t stream) {
    const float* x  = (const float*)d_in[0];
    const float* wq = (const float*)d_in[1];
    const float* wk = (const float*)d_in[2];
    const float* wv = (const float*)d_in[3];
    const float* wo = (const float*)d_in[4];
    const float* gq = (const float*)d_in[5];
    const float* gk = (const float*)d_in[6];
    const float* gv = (const float*)d_in[7];
    const float* go = (const float*)d_in[8];

    char* ws = (char*)d_ws;
    size_t off = 0;
    auto alloc = [&](size_t bytes) {
        size_t o = off;
        off += (bytes + 255) & ~(size_t)255;
        return o;
    };
    float* part = (float*)(ws + alloc(128 * 4));
    unsigned short* wbf = (unsigned short*)(ws + alloc(4ull * 1048576 * 2));   // 4 x [1024][1024] bf16
    unsigned short* abf = (unsigned short*)(ws + alloc(3ull * 4194304 * 2));   // 3 x [4096][1024] bf16
    float* asc = (float*)(ws + alloc(3ull * 4096 * 4));
    unsigned short* qbf = (unsigned short*)(ws + alloc(4194304ull * 2));       // [BH][T][D]
    unsigned short* kbf = (unsigned short*)(ws + alloc(4194304ull * 2));       // [BH][T][D]
    unsigned short* vtb = (unsigned short*)(ws + alloc(4194304ull * 2));       // [BH][D][T]
    float* ybuf = (float*)(ws + alloc(4194304ull * 4));                        // [B,T,C] f32
    unsigned short* ybf = (unsigned short*)(ws + alloc(4194304ull * 2));
    float* ysc = (float*)(ws + alloc(4096 * 4));
    (void)ws_size; (void)in_sizes; (void)n_in; (void)out_size;

    wabssum<<<128, 256, 0, stream>>>(wq, wk, wv, wo, part);
    wquant<<<256, 256, 0, stream>>>(wq, wk, wv, wo, part, wbf);
    actquant<3><<<4096, 256, 0, stream>>>(x, gq, gk, gv, abf, asc);
    gemm_bf16<0><<<1024, 256, 0, stream>>>(abf,               asc,        wbf,               part,      qbf);
    gemm_bf16<0><<<1024, 256, 0, stream>>>(abf + 4194304,     asc + 4096, wbf + 1048576,     part + 32, kbf);
    gemm_bf16<1><<<1024, 256, 0, stream>>>(abf + 2 * 4194304, asc + 8192, wbf + 2 * 1048576, part + 64, vtb);
    attn<<<2048, 256, 0, stream>>>(qbf, kbf, vtb, ybuf);
    actquant<1><<<4096, 256, 0, stream>>>(ybuf, go, go, go, ybf, ysc);
    gemm_bf16<2><<<1024, 256, 0, stream>>>(ybf, ysc, wbf + 3 * 1048576, part + 96, (float*)d_out);
}

// Round 5
// 233.868 us; speedup vs baseline: 2.5911x; 2.5911x over previous
//
#include <hip/hip_runtime.h>
#include <hip/hip_bf16.h>

// B=2, T=2048, C=1024, H=16, D=64, M=B*T=4096
// All GEMMs: exact integer math via bf16 MFMA (ints <= 2^24 exact in fp32 accum).

typedef __attribute__((ext_vector_type(8))) short bf16x8;
typedef __attribute__((ext_vector_type(4))) float f32x4;

__device__ __forceinline__ f32x4 mfma16(bf16x8 a, bf16x8 b, f32x4 c) {
    return __builtin_amdgcn_mfma_f32_16x16x32_bf16(a, b, c, 0, 0, 0);
}

__device__ __forceinline__ unsigned short f2bf(float f) {
    unsigned int u = __float_as_uint(f);
    unsigned int r = (u + 0x7fffu + ((u >> 16) & 1u)) >> 16;
    return (unsigned short)r;
}

__device__ __forceinline__ unsigned int cvtpk_bf16(float lo, float hi) {
    unsigned int r;
    asm("v_cvt_pk_bf16_f32 %0, %1, %2" : "=v"(r) : "v"(lo), "v"(hi));
    return r;
}

__device__ __forceinline__ void gload_lds16(const unsigned short* g, unsigned short* l) {
    __builtin_amdgcn_global_load_lds((const __attribute__((address_space(1))) unsigned int*)g,
                                     (__attribute__((address_space(3))) unsigned int*)l, 16, 0, 0);
}

__device__ __forceinline__ float wredsum(float v) {
#pragma unroll
    for (int o = 32; o > 0; o >>= 1) v += __shfl_xor(v, o);
    return v;
}
__device__ __forceinline__ float wredmax(float v) {
#pragma unroll
    for (int o = 32; o > 0; o >>= 1) v = fmaxf(v, __shfl_xor(v, o));
    return v;
}

// ---------------- weight absmean partials (deterministic two-pass) ----------
__global__ __launch_bounds__(256) void wabssum(const float* __restrict__ w0, const float* __restrict__ w1,
                                               const float* __restrict__ w2, const float* __restrict__ w3,
                                               float* __restrict__ part) {
    int widx = blockIdx.x >> 5, b = blockIdx.x & 31;
    const float* w = (widx == 0) ? w0 : (widx == 1) ? w1 : (widx == 2) ? w2 : w3;
    const float4* w4 = (const float4*)w;
    int tid = threadIdx.x;
    float s = 0.f;
    int base = b * 8192 + tid;  // float4 units; 32 blocks * 8192 = 262144 = 1M floats
#pragma unroll
    for (int i = 0; i < 32; ++i) {
        float4 v = w4[base + i * 256];
        s += fabsf(v.x) + fabsf(v.y) + fabsf(v.z) + fabsf(v.w);
    }
    s = wredsum(s);
    __shared__ float red[4];
    int wid = tid >> 6, lid = tid & 63;
    if (lid == 0) red[wid] = s;
    __syncthreads();
    if (tid == 0) part[blockIdx.x] = red[0] + red[1] + red[2] + red[3];
}

// ---------------- ternary weight quant -> bf16 {-1,0,1} ---------------------
__global__ __launch_bounds__(256) void wquant(const float* __restrict__ w0, const float* __restrict__ w1,
                                              const float* __restrict__ w2, const float* __restrict__ w3,
                                              const float* __restrict__ part, unsigned short* __restrict__ wbf) {
    int widx = blockIdx.x >> 6, b = blockIdx.x & 63;
    const float* w = (widx == 0) ? w0 : (widx == 1) ? w1 : (widx == 2) ? w2 : w3;
    float s = 0.f;
#pragma unroll
    for (int i = 0; i < 32; ++i) s += part[widx * 32 + i];
    s = fmaxf(s * (1.f / 1048576.f), 1e-5f);
    float inv = 1.f / s;
    const float4* w4 = (const float4*)w;
    unsigned short* dst = wbf + (size_t)widx * 1048576;
    int tid = threadIdx.x;
#pragma unroll
    for (int it = 0; it < 16; ++it) {
        int i4 = b * 4096 + it * 256 + tid;
        float4 v = w4[i4];
        float q0 = fminf(fmaxf(rintf(v.x * inv), -1.f), 1.f);
        float q1 = fminf(fmaxf(rintf(v.y * inv), -1.f), 1.f);
        float q2 = fminf(fmaxf(rintf(v.z * inv), -1.f), 1.f);
        float q3 = fminf(fmaxf(rintf(v.w * inv), -1.f), 1.f);
        ((ushort4*)dst)[i4] = make_ushort4(f2bf(q0), f2bf(q1), f2bf(q2), f2bf(q3));
    }
}

// ------------- fused rmsnorm + per-token absmax quant (NP planes) -----------
template <int NP>
__global__ __launch_bounds__(256) void actquant(const float* __restrict__ x, const float* __restrict__ g0,
                                                const float* __restrict__ g1, const float* __restrict__ g2,
                                                unsigned short* __restrict__ aq, float* __restrict__ ascale) {
    int m = blockIdx.x, tid = threadIdx.x;
    int wid = tid >> 6, lid = tid & 63;
    __shared__ float red[4];
    float4 xv = ((const float4*)(x + (size_t)m * 1024))[tid];
    float ss = xv.x * xv.x + xv.y * xv.y + xv.z * xv.z + xv.w * xv.w;
    ss = wredsum(ss);
    if (lid == 0) red[wid] = ss;
    __syncthreads();
    float rstd = rsqrtf((red[0] + red[1] + red[2] + red[3]) * (1.f / 1024.f) + 1e-6f);
    const float* gs[3] = {g0, g1, g2};
#pragma unroll
    for (int p = 0; p < NP; ++p) {
        float4 gv = ((const float4*)gs[p])[tid];
        float a0 = xv.x * gv.x * rstd, a1 = xv.y * gv.y * rstd;
        float a2 = xv.z * gv.z * rstd, a3 = xv.w * gv.w * rstd;
        float am = fmaxf(fmaxf(fabsf(a0), fabsf(a1)), fmaxf(fabsf(a2), fabsf(a3)));
        am = wredmax(am);
        __syncthreads();  // protect red from previous use
        if (lid == 0) red[wid] = am;
        __syncthreads();
        float rm = fmaxf(fmaxf(red[0], red[1]), fmaxf(red[2], red[3]));
        float scale = 127.f / fmaxf(rm, 1e-5f);
        float q0 = fminf(fmaxf(rintf(a0 * scale), -128.f), 127.f);
        float q1 = fminf(fmaxf(rintf(a1 * scale), -128.f), 127.f);
        float q2 = fminf(fmaxf(rintf(a2 * scale), -128.f), 127.f);
        float q3 = fminf(fmaxf(rintf(a3 * scale), -128.f), 127.f);
        ((ushort4*)(aq + (size_t)p * 4194304 + (size_t)m * 1024))[tid] =
            make_ushort4(f2bf(q0), f2bf(q1), f2bf(q2), f2bf(q3));
        if (tid == 0) ascale[p * 4096 + m] = scale;
    }
}

// ------------- 128x128-tile GEMM core (m97 structure) -----------------------
// BK=64, 256 thr = 2x2 waves, 4x4 16x16 frags/wave, linear LDS + global_load_lds.
// MODE 0: out bf16 [B,H,T,D]; MODE 1: out bf16 [BH,D,T]; MODE 2: out f32 [M,N]
template <int MODE>
__device__ __forceinline__ void gemm_core(const unsigned short* __restrict__ A,
                                          const float* __restrict__ asc,
                                          const unsigned short* __restrict__ W, float s_w,
                                          void* __restrict__ outp, int bm, int bn,
                                          unsigned short* As, unsigned short* Bs) {
    int tid = threadIdx.x;
    int w = tid >> 6, l = tid & 63;
    int wr = w >> 1, wc = w & 1;
    int lr = l & 15, lh = l >> 4;
    f32x4 acc[4][4] = {};
    int srow = l >> 3;         // 0..7
    int scol = (l & 7) * 8;    // short offset
    const unsigned short* Ab = A + (size_t)(bm * 128) * 1024;
    const unsigned short* Wb = W + (size_t)(bn * 128) * 1024;

    for (int kt = 0; kt < 16; ++kt) {
        int k0 = kt * 64;
        __syncthreads();  // all waves done reading LDS from prev iter
#pragma unroll
        for (int j = 0; j < 4; ++j) {
            int c = j * 4 + w;  // 1KB chunk, wave-uniform LDS base
            gload_lds16(Ab + (size_t)(c * 8 + srow) * 1024 + k0 + scol, &As[c * 512]);
            gload_lds16(Wb + (size_t)(c * 8 + srow) * 1024 + k0 + scol, &Bs[c * 512]);
        }
        __syncthreads();  // vmcnt(0) drain + barrier: tile ready
#pragma unroll
        for (int ks = 0; ks < 2; ++ks) {
            int kb = ks * 32 + lh * 8;
            bf16x8 af[4], bfr[4];
#pragma unroll
            for (int mi = 0; mi < 4; ++mi) af[mi] = *(const bf16x8*)&As[(wr * 64 + mi * 16 + lr) * 64 + kb];
#pragma unroll
            for (int ni = 0; ni < 4; ++ni) bfr[ni] = *(const bf16x8*)&Bs[(wc * 64 + ni * 16 + lr) * 64 + kb];
#pragma unroll
            for (int mi = 0; mi < 4; ++mi)
#pragma unroll
                for (int ni = 0; ni < 4; ++ni) acc[mi][ni] = mfma16(af[mi], bfr[ni], acc[mi][ni]);
        }
    }
#pragma unroll
    for (int mi = 0; mi < 4; ++mi) {
        int mbase = bm * 128 + wr * 64 + mi * 16 + lh * 4;
#pragma unroll
        for (int ni = 0; ni < 4; ++ni) {
            int n = bn * 128 + wc * 64 + ni * 16 + lr;
            if (MODE == 1) {
                int b = mbase >> 11, t0 = mbase & 2047;
                int h = n >> 6, d = n & 63;
                ushort4 st;
                st.x = f2bf(acc[mi][ni][0] * s_w / asc[mbase + 0]);
                st.y = f2bf(acc[mi][ni][1] * s_w / asc[mbase + 1]);
                st.z = f2bf(acc[mi][ni][2] * s_w / asc[mbase + 2]);
                st.w = f2bf(acc[mi][ni][3] * s_w / asc[mbase + 3]);
                *(ushort4*)&((unsigned short*)outp)[(size_t)(b * 16 + h) * 131072 + (size_t)d * 2048 + t0] = st;
            } else {
#pragma unroll
                for (int i = 0; i < 4; ++i) {
                    int m = mbase + i;
                    float val = acc[mi][ni][i] * s_w / asc[m];
                    if (MODE == 0) {
                        int b = m >> 11, t = m & 2047, h = n >> 6, d = n & 63;
                        ((unsigned short*)outp)[(size_t)(b * 16 + h) * 131072 + (size_t)t * 64 + d] = f2bf(val);
                    } else {
                        ((float*)outp)[(size_t)m * 1024 + n] = val;
                    }
                }
            }
        }
    }
}

__device__ __forceinline__ float sw_from_part(const float* part) {
    float s = 0.f;
#pragma unroll
    for (int i = 0; i < 32; ++i) s += part[i];
    return fmaxf(s * (1.f / 1048576.f), 1e-5f);
}

// fused Q/K/V projection: blockIdx.z picks the gemm (0=q,1=k,2=v)
__global__ __launch_bounds__(256) void gemm_qkv(const unsigned short* __restrict__ abf,
                                                const float* __restrict__ ascale,
                                                const unsigned short* __restrict__ wbf,
                                                const float* __restrict__ part,
                                                unsigned short* __restrict__ qbf,
                                                unsigned short* __restrict__ kbf,
                                                unsigned short* __restrict__ vtb) {
    __shared__ alignas(16) unsigned short As[8192];
    __shared__ alignas(16) unsigned short Bs[8192];
    int z = blockIdx.z;
    const unsigned short* A = abf + (size_t)z * 4194304;
    const float* asc = ascale + z * 4096;
    const unsigned short* W = wbf + (size_t)z * 1048576;
    float s_w = sw_from_part(part + z * 32);
    int bm = blockIdx.x, bn = blockIdx.y;
    if (z == 0) {
        gemm_core<0>(A, asc, W, s_w, qbf, bm, bn, As, Bs);
    } else if (z == 1) {
        gemm_core<0>(A, asc, W, s_w, kbf, bm, bn, As, Bs);
    } else {
        gemm_core<1>(A, asc, W, s_w, vtb, bm, bn, As, Bs);
    }
}

// output projection: f32 out
__global__ __launch_bounds__(256) void gemm_o(const unsigned short* __restrict__ A,
                                              const float* __restrict__ asc,
                                              const unsigned short* __restrict__ W,
                                              const float* __restrict__ part, float* __restrict__ outp) {
    __shared__ alignas(16) unsigned short As[8192];
    __shared__ alignas(16) unsigned short Bs[8192];
    float s_w = sw_from_part(part);
    gemm_core<2>(A, asc, W, s_w, outp, blockIdx.x, blockIdx.y, As, Bs);
}

// ---------------- flash attention (causal, 16 heads, D=64) ------------------
// 1 wave per block, one 16-row q-chunk, heavy chunks first. Swapped QK^T:
// S^T = mfma(K,Q) so each lane holds the P-row of q = lane&15 in registers;
// softmax = in-lane reduce + 2 shfl_xor. P -> LDS via cvt_pk + 2x ds_write_b64.
__global__ __launch_bounds__(64) void attn(const unsigned short* __restrict__ qb,
                                           const unsigned short* __restrict__ kb,
                                           const unsigned short* __restrict__ vt, float* __restrict__ y) {
    int blk = blockIdx.x;
    int bh = blk & 31;
    int c = 127 - (blk >> 5);  // chunk 0..127, heaviest first
    int q0 = c << 4;
    int l = threadIdx.x & 63;
    int lr = l & 15, lh = l >> 4;
    const unsigned short* qbase = qb + (size_t)bh * 131072;
    const unsigned short* kbase = kb + (size_t)bh * 131072;
    const unsigned short* vbase = vt + (size_t)bh * 131072;

    bf16x8 qf0 = *(const bf16x8*)&qbase[(size_t)(q0 + lr) * 64 + lh * 8];
    bf16x8 qf1 = *(const bf16x8*)&qbase[(size_t)(q0 + lr) * 64 + 32 + lh * 8];

    f32x4 o0 = {}, o1 = {}, o2 = {}, o3 = {};
    float ninf = -__builtin_inff();
    float mreg = ninf;  // running max for q-row = q0+lr
    float lreg = 0.f;   // running sum for q-row = q0+lr
    __shared__ alignas(16) unsigned short plds[16][40];  // [q][kv], stride 80B

    int qrow = q0 + lr;
    int ntiles = (q0 + 47) >> 5;

    auto LOADK = [&](int kv0, bf16x8* k) {
        k[0] = *(const bf16x8*)&kbase[(size_t)(kv0 + lr) * 64 + lh * 8];
        k[1] = *(const bf16x8*)&kbase[(size_t)(kv0 + lr) * 64 + 32 + lh * 8];
        k[2] = *(const bf16x8*)&kbase[(size_t)(kv0 + 16 + lr) * 64 + lh * 8];
        k[3] = *(const bf16x8*)&kbase[(size_t)(kv0 + 16 + lr) * 64 + 32 + lh * 8];
    };
    auto LOADV = [&](int kv0, bf16x8* v) {
        v[0] = *(const bf16x8*)&vbase[(size_t)(lr)*2048 + kv0 + lh * 8];
        v[1] = *(const bf16x8*)&vbase[(size_t)(16 + lr) * 2048 + kv0 + lh * 8];
        v[2] = *(const bf16x8*)&vbase[(size_t)(32 + lr) * 2048 + kv0 + lh * 8];
        v[3] = *(const bf16x8*)&vbase[(size_t)(48 + lr) * 2048 + kv0 + lh * 8];
    };
    auto PROCESS = [&](int t, bf16x8* k, bf16x8* v) {
        int kv0 = t << 5;
        f32x4 s0 = {}, s1 = {};
        s0 = mfma16(k[0], qf0, s0);
        s0 = mfma16(k[1], qf1, s0);
        s1 = mfma16(k[2], qf0, s1);
        s1 = mfma16(k[3], qf1, s1);
        // s0[r] = S[q0+lr][kv0 + lh*4 + r], s1[r] = S[q0+lr][kv0 + 16 + lh*4 + r]
        float p[8];
#pragma unroll
        for (int r = 0; r < 4; ++r) {
            p[r]     = (kv0 + lh * 4 + r <= qrow)      ? s0[r] * 0.125f : ninf;
            p[r + 4] = (kv0 + 16 + lh * 4 + r <= qrow) ? s1[r] * 0.125f : ninf;
        }
        float tmax = fmaxf(fmaxf(fmaxf(p[0], p[1]), fmaxf(p[2], p[3])),
                           fmaxf(fmaxf(p[4], p[5]), fmaxf(p[6], p[7])));
        tmax = fmaxf(tmax, __shfl_xor(tmax, 16));
        tmax = fmaxf(tmax, __shfl_xor(tmax, 32));
        float mn = fmaxf(mreg, tmax);
        float cc = __expf(mreg - mn);
        float ps[8];
#pragma unroll
        for (int r = 0; r < 8; ++r) ps[r] = __expf(p[r] - mn);
        float sum = ((ps[0] + ps[1]) + (ps[2] + ps[3])) + ((ps[4] + ps[5]) + (ps[6] + ps[7]));
        sum += __shfl_xor(sum, 16);
        sum += __shfl_xor(sum, 32);
        lreg = lreg * cc + sum;
        mreg = mn;
        // pack + store P^T transpose via LDS: plds[q=lr][kv_rel]
        uint2 wlo, whi;
        wlo.x = cvtpk_bf16(ps[0], ps[1]);
        wlo.y = cvtpk_bf16(ps[2], ps[3]);
        whi.x = cvtpk_bf16(ps[4], ps[5]);
        whi.y = cvtpk_bf16(ps[6], ps[7]);
        *(uint2*)&plds[lr][lh * 4] = wlo;
        *(uint2*)&plds[lr][16 + lh * 4] = whi;
        // rescale O
#pragma unroll
        for (int r = 0; r < 4; ++r) {
            o0[r] *= cc; o1[r] *= cc; o2[r] *= cc; o3[r] *= cc;
        }
        bf16x8 pf = *(const bf16x8*)&plds[lr][lh * 8];
        o0 = mfma16(v[0], pf, o0);
        o1 = mfma16(v[1], pf, o1);
        o2 = mfma16(v[2], pf, o2);
        o3 = mfma16(v[3], pf, o3);
    };

    bf16x8 kA[4], vA[4], kB[4], vB[4];
    LOADK(0, kA);
    LOADV(0, vA);
    int t = 0;
    while (true) {
        if (t + 1 < ntiles) { LOADK((t + 1) << 5, kB); LOADV((t + 1) << 5, vB); }
        PROCESS(t, kA, vA);
        if (++t >= ntiles) break;
        if (t + 1 < ntiles) { LOADK((t + 1) << 5, kA); LOADV((t + 1) << 5, vA); }
        PROCESS(t, kB, vB);
        if (++t >= ntiles) break;
    }

    int b = bh >> 4, h = bh & 15;
    float invl = 1.f / lreg;
    float* yr = y + (size_t)(b * 2048 + qrow) * 1024 + h * 64;
    // o_di[r] = O[q=lr][d = di*16 + lh*4 + r]
    float4 st;
    st.x = o0[0] * invl; st.y = o0[1] * invl; st.z = o0[2] * invl; st.w = o0[3] * invl;
    *(float4*)&yr[lh * 4] = st;
    st.x = o1[0] * invl; st.y = o1[1] * invl; st.z = o1[2] * invl; st.w = o1[3] * invl;
    *(float4*)&yr[16 + lh * 4] = st;
    st.x = o2[0] * invl; st.y = o2[1] * invl; st.z = o2[2] * invl; st.w = o2[3] * invl;
    *(float4*)&yr[32 + lh * 4] = st;
    st.x = o3[0] * invl; st.y = o3[1] * invl; st.z = o3[2] * invl; st.w = o3[3] * invl;
    *(float4*)&yr[48 + lh * 4] = st;
}

extern "C" void kernel_launch(void* const* d_in, const int* in_sizes, int n_in,
                              void* d_out, int out_size, void* d_ws, size_t ws_size,
                              hipStream_t stream) {
    const float* x  = (const float*)d_in[0];
    const float* wq = (const float*)d_in[1];
    const float* wk = (const float*)d_in[2];
    const float* wv = (const float*)d_in[3];
    const float* wo = (const float*)d_in[4];
    const float* gq = (const float*)d_in[5];
    const float* gk = (const float*)d_in[6];
    const float* gv = (const float*)d_in[7];
    const float* go = (const float*)d_in[8];

    char* ws = (char*)d_ws;
    size_t off = 0;
    auto alloc = [&](size_t bytes) {
        size_t o = off;
        off += (bytes + 255) & ~(size_t)255;
        return o;
    };
    float* part = (float*)(ws + alloc(128 * 4));
    unsigned short* wbf = (unsigned short*)(ws + alloc(4ull * 1048576 * 2));   // 4 x [1024][1024] bf16
    unsigned short* abf = (unsigned short*)(ws + alloc(3ull * 4194304 * 2));   // 3 x [4096][1024] bf16
    float* asc = (float*)(ws + alloc(3ull * 4096 * 4));
    unsigned short* qbf = (unsigned short*)(ws + alloc(4194304ull * 2));       // [BH][T][D]
    unsigned short* kbf = (unsigned short*)(ws + alloc(4194304ull * 2));       // [BH][T][D]
    unsigned short* vtb = (unsigned short*)(ws + alloc(4194304ull * 2));       // [BH][D][T]
    float* ybuf = (float*)(ws + alloc(4194304ull * 4));                        // [B,T,C] f32
    unsigned short* ybf = (unsigned short*)(ws + alloc(4194304ull * 2));
    float* ysc = (float*)(ws + alloc(4096 * 4));
    (void)ws_size; (void)in_sizes; (void)n_in; (void)out_size;

    wabssum<<<128, 256, 0, stream>>>(wq, wk, wv, wo, part);
    wquant<<<256, 256, 0, stream>>>(wq, wk, wv, wo, part, wbf);
    actquant<3><<<4096, 256, 0, stream>>>(x, gq, gk, gv, abf, asc);
    gemm_qkv<<<dim3(32, 8, 3), 256, 0, stream>>>(abf, asc, wbf, part, qbf, kbf, vtb);
    attn<<<4096, 64, 0, stream>>>(qbf, kbf, vtb, ybuf);
    actquant<1><<<4096, 256, 0, stream>>>(ybuf, go, go, go, ybf, ysc);
    gemm_o<<<dim3(32, 8), 256, 0, stream>>>(ybf, ysc, wbf + 3 * 1048576, part + 96, (float*)d_out);
}

// Round 6
// 186.706 us; speedup vs baseline: 3.2456x; 1.2526x over previous
//
#include <hip/hip_runtime.h>
#include <hip/hip_bf16.h>

// B=2, T=2048, C=1024, H=16, D=64, M=B*T=4096
// All GEMMs: exact integer math via bf16 MFMA (ints <= 2^24 exact in fp32 accum).

typedef __attribute__((ext_vector_type(8))) short bf16x8;
typedef __attribute__((ext_vector_type(4))) float f32x4;

__device__ __forceinline__ f32x4 mfma16(bf16x8 a, bf16x8 b, f32x4 c) {
    return __builtin_amdgcn_mfma_f32_16x16x32_bf16(a, b, c, 0, 0, 0);
}

__device__ __forceinline__ unsigned short f2bf(float f) {
    unsigned int u = __float_as_uint(f);
    unsigned int r = (u + 0x7fffu + ((u >> 16) & 1u)) >> 16;
    return (unsigned short)r;
}

__device__ __forceinline__ unsigned int cvtpk_bf16(float lo, float hi) {
    unsigned int r;
    asm("v_cvt_pk_bf16_f32 %0, %1, %2" : "=v"(r) : "v"(lo), "v"(hi));
    return r;
}

__device__ __forceinline__ void gload_lds16(const unsigned short* g, unsigned short* l) {
    __builtin_amdgcn_global_load_lds((const __attribute__((address_space(1))) unsigned int*)g,
                                     (__attribute__((address_space(3))) unsigned int*)l, 16, 0, 0);
}

__device__ __forceinline__ float wredsum(float v) {
#pragma unroll
    for (int o = 32; o > 0; o >>= 1) v += __shfl_xor(v, o);
    return v;
}
__device__ __forceinline__ float wredmax(float v) {
#pragma unroll
    for (int o = 32; o > 0; o >>= 1) v = fmaxf(v, __shfl_xor(v, o));
    return v;
}

// ---------------- weight absmean partials (deterministic two-pass) ----------
__global__ __launch_bounds__(256) void wabssum(const float* __restrict__ w0, const float* __restrict__ w1,
                                               const float* __restrict__ w2, const float* __restrict__ w3,
                                               float* __restrict__ part) {
    int widx = blockIdx.x >> 5, b = blockIdx.x & 31;
    const float* w = (widx == 0) ? w0 : (widx == 1) ? w1 : (widx == 2) ? w2 : w3;
    const float4* w4 = (const float4*)w;
    int tid = threadIdx.x;
    float s = 0.f;
    int base = b * 8192 + tid;  // float4 units; 32 blocks * 8192 = 262144 = 1M floats
#pragma unroll
    for (int i = 0; i < 32; ++i) {
        float4 v = w4[base + i * 256];
        s += fabsf(v.x) + fabsf(v.y) + fabsf(v.z) + fabsf(v.w);
    }
    s = wredsum(s);
    __shared__ float red[4];
    int wid = tid >> 6, lid = tid & 63;
    if (lid == 0) red[wid] = s;
    __syncthreads();
    if (tid == 0) part[blockIdx.x] = red[0] + red[1] + red[2] + red[3];
}

// ---------------- ternary weight quant -> bf16 {-1,0,1} ---------------------
__global__ __launch_bounds__(256) void wquant(const float* __restrict__ w0, const float* __restrict__ w1,
                                              const float* __restrict__ w2, const float* __restrict__ w3,
                                              const float* __restrict__ part, unsigned short* __restrict__ wbf) {
    int widx = blockIdx.x >> 6, b = blockIdx.x & 63;
    const float* w = (widx == 0) ? w0 : (widx == 1) ? w1 : (widx == 2) ? w2 : w3;
    float s = 0.f;
#pragma unroll
    for (int i = 0; i < 32; ++i) s += part[widx * 32 + i];
    s = fmaxf(s * (1.f / 1048576.f), 1e-5f);
    float inv = 1.f / s;
    const float4* w4 = (const float4*)w;
    unsigned short* dst = wbf + (size_t)widx * 1048576;
    int tid = threadIdx.x;
#pragma unroll
    for (int it = 0; it < 16; ++it) {
        int i4 = b * 4096 + it * 256 + tid;
        float4 v = w4[i4];
        float q0 = fminf(fmaxf(rintf(v.x * inv), -1.f), 1.f);
        float q1 = fminf(fmaxf(rintf(v.y * inv), -1.f), 1.f);
        float q2 = fminf(fmaxf(rintf(v.z * inv), -1.f), 1.f);
        float q3 = fminf(fmaxf(rintf(v.w * inv), -1.f), 1.f);
        ((ushort4*)dst)[i4] = make_ushort4(f2bf(q0), f2bf(q1), f2bf(q2), f2bf(q3));
    }
}

// ------------- fused rmsnorm + per-token absmax quant (NP planes) -----------
template <int NP>
__global__ __launch_bounds__(256) void actquant(const float* __restrict__ x, const float* __restrict__ g0,
                                                const float* __restrict__ g1, const float* __restrict__ g2,
                                                unsigned short* __restrict__ aq, float* __restrict__ ascale) {
    int m = blockIdx.x, tid = threadIdx.x;
    int wid = tid >> 6, lid = tid & 63;
    __shared__ float red[4];
    float4 xv = ((const float4*)(x + (size_t)m * 1024))[tid];
    float ss = xv.x * xv.x + xv.y * xv.y + xv.z * xv.z + xv.w * xv.w;
    ss = wredsum(ss);
    if (lid == 0) red[wid] = ss;
    __syncthreads();
    float rstd = rsqrtf((red[0] + red[1] + red[2] + red[3]) * (1.f / 1024.f) + 1e-6f);
    const float* gs[3] = {g0, g1, g2};
#pragma unroll
    for (int p = 0; p < NP; ++p) {
        float4 gv = ((const float4*)gs[p])[tid];
        float a0 = xv.x * gv.x * rstd, a1 = xv.y * gv.y * rstd;
        float a2 = xv.z * gv.z * rstd, a3 = xv.w * gv.w * rstd;
        float am = fmaxf(fmaxf(fabsf(a0), fabsf(a1)), fmaxf(fabsf(a2), fabsf(a3)));
        am = wredmax(am);
        __syncthreads();  // protect red from previous use
        if (lid == 0) red[wid] = am;
        __syncthreads();
        float rm = fmaxf(fmaxf(red[0], red[1]), fmaxf(red[2], red[3]));
        float scale = 127.f / fmaxf(rm, 1e-5f);
        float q0 = fminf(fmaxf(rintf(a0 * scale), -128.f), 127.f);
        float q1 = fminf(fmaxf(rintf(a1 * scale), -128.f), 127.f);
        float q2 = fminf(fmaxf(rintf(a2 * scale), -128.f), 127.f);
        float q3 = fminf(fmaxf(rintf(a3 * scale), -128.f), 127.f);
        ((ushort4*)(aq + (size_t)p * 4194304 + (size_t)m * 1024))[tid] =
            make_ushort4(f2bf(q0), f2bf(q1), f2bf(q2), f2bf(q3));
        if (tid == 0) ascale[p * 4096 + m] = scale;
    }
}

// ------------- 128x128-tile GEMM core (m97 structure) -----------------------
// BK=64, 256 thr = 2x2 waves, 4x4 16x16 frags/wave, linear LDS + global_load_lds.
// MODE 0: out bf16 [B,H,T,D]; MODE 1: out bf16 [BH,D,T]; MODE 2: out f32 [M,N]
template <int MODE>
__device__ __forceinline__ void gemm_core(const unsigned short* __restrict__ A,
                                          const float* __restrict__ asc,
                                          const unsigned short* __restrict__ W, float s_w,
                                          void* __restrict__ outp, int bm, int bn,
                                          unsigned short* As, unsigned short* Bs) {
    int tid = threadIdx.x;
    int w = tid >> 6, l = tid & 63;
    int wr = w >> 1, wc = w & 1;
    int lr = l & 15, lh = l >> 4;
    f32x4 acc[4][4] = {};
    int srow = l >> 3;         // 0..7
    int scol = (l & 7) * 8;    // short offset
    const unsigned short* Ab = A + (size_t)(bm * 128) * 1024;
    const unsigned short* Wb = W + (size_t)(bn * 128) * 1024;

    for (int kt = 0; kt < 16; ++kt) {
        int k0 = kt * 64;
        __syncthreads();  // all waves done reading LDS from prev iter
#pragma unroll
        for (int j = 0; j < 4; ++j) {
            int c = j * 4 + w;  // 1KB chunk, wave-uniform LDS base
            gload_lds16(Ab + (size_t)(c * 8 + srow) * 1024 + k0 + scol, &As[c * 512]);
            gload_lds16(Wb + (size_t)(c * 8 + srow) * 1024 + k0 + scol, &Bs[c * 512]);
        }
        __syncthreads();  // vmcnt(0) drain + barrier: tile ready
#pragma unroll
        for (int ks = 0; ks < 2; ++ks) {
            int kb = ks * 32 + lh * 8;
            bf16x8 af[4], bfr[4];
#pragma unroll
            for (int mi = 0; mi < 4; ++mi) af[mi] = *(const bf16x8*)&As[(wr * 64 + mi * 16 + lr) * 64 + kb];
#pragma unroll
            for (int ni = 0; ni < 4; ++ni) bfr[ni] = *(const bf16x8*)&Bs[(wc * 64 + ni * 16 + lr) * 64 + kb];
#pragma unroll
            for (int mi = 0; mi < 4; ++mi)
#pragma unroll
                for (int ni = 0; ni < 4; ++ni) acc[mi][ni] = mfma16(af[mi], bfr[ni], acc[mi][ni]);
        }
    }
#pragma unroll
    for (int mi = 0; mi < 4; ++mi) {
        int mbase = bm * 128 + wr * 64 + mi * 16 + lh * 4;
#pragma unroll
        for (int ni = 0; ni < 4; ++ni) {
            int n = bn * 128 + wc * 64 + ni * 16 + lr;
            if (MODE == 1) {
                int b = mbase >> 11, t0 = mbase & 2047;
                int h = n >> 6, d = n & 63;
                ushort4 st;
                st.x = f2bf(acc[mi][ni][0] * s_w / asc[mbase + 0]);
                st.y = f2bf(acc[mi][ni][1] * s_w / asc[mbase + 1]);
                st.z = f2bf(acc[mi][ni][2] * s_w / asc[mbase + 2]);
                st.w = f2bf(acc[mi][ni][3] * s_w / asc[mbase + 3]);
                *(ushort4*)&((unsigned short*)outp)[(size_t)(b * 16 + h) * 131072 + (size_t)d * 2048 + t0] = st;
            } else {
#pragma unroll
                for (int i = 0; i < 4; ++i) {
                    int m = mbase + i;
                    float val = acc[mi][ni][i] * s_w / asc[m];
                    if (MODE == 0) {
                        int b = m >> 11, t = m & 2047, h = n >> 6, d = n & 63;
                        ((unsigned short*)outp)[(size_t)(b * 16 + h) * 131072 + (size_t)t * 64 + d] = f2bf(val);
                    } else {
                        ((float*)outp)[(size_t)m * 1024 + n] = val;
                    }
                }
            }
        }
    }
}

__device__ __forceinline__ float sw_from_part(const float* part) {
    float s = 0.f;
#pragma unroll
    for (int i = 0; i < 32; ++i) s += part[i];
    return fmaxf(s * (1.f / 1048576.f), 1e-5f);
}

// fused Q/K/V projection: blockIdx.z picks the gemm (0=q,1=k,2=v)
__global__ __launch_bounds__(256) void gemm_qkv(const unsigned short* __restrict__ abf,
                                                const float* __restrict__ ascale,
                                                const unsigned short* __restrict__ wbf,
                                                const float* __restrict__ part,
                                                unsigned short* __restrict__ qbf,
                                                unsigned short* __restrict__ kbf,
                                                unsigned short* __restrict__ vtb) {
    __shared__ alignas(16) unsigned short As[8192];
    __shared__ alignas(16) unsigned short Bs[8192];
    int z = blockIdx.z;
    const unsigned short* A = abf + (size_t)z * 4194304;
    const float* asc = ascale + z * 4096;
    const unsigned short* W = wbf + (size_t)z * 1048576;
    float s_w = sw_from_part(part + z * 32);
    int bm = blockIdx.x, bn = blockIdx.y;
    if (z == 0) {
        gemm_core<0>(A, asc, W, s_w, qbf, bm, bn, As, Bs);
    } else if (z == 1) {
        gemm_core<0>(A, asc, W, s_w, kbf, bm, bn, As, Bs);
    } else {
        gemm_core<1>(A, asc, W, s_w, vtb, bm, bn, As, Bs);
    }
}

// output projection: f32 out
__global__ __launch_bounds__(256) void gemm_o(const unsigned short* __restrict__ A,
                                              const float* __restrict__ asc,
                                              const unsigned short* __restrict__ W,
                                              const float* __restrict__ part, float* __restrict__ outp) {
    __shared__ alignas(16) unsigned short As[8192];
    __shared__ alignas(16) unsigned short Bs[8192];
    float s_w = sw_from_part(part);
    gemm_core<2>(A, asc, W, s_w, outp, blockIdx.x, blockIdx.y, As, Bs);
}

// ---------------- flash attention (causal, 16 heads, D=64) ------------------
// 1 wave per block, 32 q-rows per wave (two 16-row MFMA fragments sharing one
// K/V stream -> half the K/V cache traffic of 16q/wave). Heavy chunks first.
// Swapped QK^T: S^T = mfma(K,Q); per-lane in-register softmax per q-fragment.
__global__ __launch_bounds__(64) void attn(const unsigned short* __restrict__ qb,
                                           const unsigned short* __restrict__ kb,
                                           const unsigned short* __restrict__ vt, float* __restrict__ y) {
    int blk = blockIdx.x;
    int bh = blk & 31;
    int c = 63 - (blk >> 5);  // 32-row chunk 0..63, heaviest first
    int q0 = c << 5;
    int l = threadIdx.x & 63;
    int lr = l & 15, lh = l >> 4;
    const unsigned short* qbase = qb + (size_t)bh * 131072;
    const unsigned short* kbase = kb + (size_t)bh * 131072;
    const unsigned short* vbase = vt + (size_t)bh * 131072;

    // Q fragments: qf[qt][ks], q-row = q0 + qt*16 + lr
    bf16x8 qf00 = *(const bf16x8*)&qbase[(size_t)(q0 + lr) * 64 + lh * 8];
    bf16x8 qf01 = *(const bf16x8*)&qbase[(size_t)(q0 + lr) * 64 + 32 + lh * 8];
    bf16x8 qf10 = *(const bf16x8*)&qbase[(size_t)(q0 + 16 + lr) * 64 + lh * 8];
    bf16x8 qf11 = *(const bf16x8*)&qbase[(size_t)(q0 + 16 + lr) * 64 + 32 + lh * 8];

    f32x4 o[4][2] = {};  // [dt][qt]
    float ninf = -__builtin_inff();
    float mreg0 = ninf, mreg1 = ninf;
    float lreg0 = 0.f, lreg1 = 0.f;
    __shared__ alignas(16) unsigned short plds[2][16][40];

    int qrow0 = q0 + lr, qrow1 = q0 + 16 + lr;
    int ntiles = c + 1;

    auto LOADK = [&](int kv0, bf16x8* k) {
        k[0] = *(const bf16x8*)&kbase[(size_t)(kv0 + lr) * 64 + lh * 8];
        k[1] = *(const bf16x8*)&kbase[(size_t)(kv0 + lr) * 64 + 32 + lh * 8];
        k[2] = *(const bf16x8*)&kbase[(size_t)(kv0 + 16 + lr) * 64 + lh * 8];
        k[3] = *(const bf16x8*)&kbase[(size_t)(kv0 + 16 + lr) * 64 + 32 + lh * 8];
    };
    auto LOADV = [&](int kv0, bf16x8* v) {
        v[0] = *(const bf16x8*)&vbase[(size_t)(lr)*2048 + kv0 + lh * 8];
        v[1] = *(const bf16x8*)&vbase[(size_t)(16 + lr) * 2048 + kv0 + lh * 8];
        v[2] = *(const bf16x8*)&vbase[(size_t)(32 + lr) * 2048 + kv0 + lh * 8];
        v[3] = *(const bf16x8*)&vbase[(size_t)(48 + lr) * 2048 + kv0 + lh * 8];
    };
    // per-q-fragment softmax: returns rescale factor, updates m/l, writes plds[qt]
    auto SOFTMAX = [&](int kv0, int qrow, float& mreg, float& lreg, f32x4 s0, f32x4 s1,
                       unsigned short(*pl)[40]) -> float {
        float p[8];
#pragma unroll
        for (int r = 0; r < 4; ++r) {
            p[r]     = (kv0 + lh * 4 + r <= qrow)      ? s0[r] * 0.125f : ninf;
            p[r + 4] = (kv0 + 16 + lh * 4 + r <= qrow) ? s1[r] * 0.125f : ninf;
        }
        float tmax = fmaxf(fmaxf(fmaxf(p[0], p[1]), fmaxf(p[2], p[3])),
                           fmaxf(fmaxf(p[4], p[5]), fmaxf(p[6], p[7])));
        tmax = fmaxf(tmax, __shfl_xor(tmax, 16));
        tmax = fmaxf(tmax, __shfl_xor(tmax, 32));
        float mn = fmaxf(mreg, tmax);
        float cc = __expf(mreg - mn);
        float ps[8];
#pragma unroll
        for (int r = 0; r < 8; ++r) ps[r] = __expf(p[r] - mn);
        float sum = ((ps[0] + ps[1]) + (ps[2] + ps[3])) + ((ps[4] + ps[5]) + (ps[6] + ps[7]));
        sum += __shfl_xor(sum, 16);
        sum += __shfl_xor(sum, 32);
        lreg = lreg * cc + sum;
        mreg = mn;
        uint2 wlo, whi;
        wlo.x = cvtpk_bf16(ps[0], ps[1]);
        wlo.y = cvtpk_bf16(ps[2], ps[3]);
        whi.x = cvtpk_bf16(ps[4], ps[5]);
        whi.y = cvtpk_bf16(ps[6], ps[7]);
        *(uint2*)&pl[lr][lh * 4] = wlo;
        *(uint2*)&pl[lr][16 + lh * 4] = whi;
        return cc;
    };
    auto PROCESS = [&](int t, bf16x8* k, bf16x8* v) {
        int kv0 = t << 5;
        // QK^T for both q-fragments, sharing the K fragments
        f32x4 s00 = {}, s01 = {}, s10 = {}, s11 = {};
        s00 = mfma16(k[0], qf00, s00);
        s00 = mfma16(k[1], qf01, s00);
        s01 = mfma16(k[2], qf00, s01);
        s01 = mfma16(k[3], qf01, s01);
        s10 = mfma16(k[0], qf10, s10);
        s10 = mfma16(k[1], qf11, s10);
        s11 = mfma16(k[2], qf10, s11);
        s11 = mfma16(k[3], qf11, s11);
        float cc0 = SOFTMAX(kv0, qrow0, mreg0, lreg0, s00, s01, plds[0]);
        float cc1 = SOFTMAX(kv0, qrow1, mreg1, lreg1, s10, s11, plds[1]);
        bf16x8 pf0 = *(const bf16x8*)&plds[0][lr][lh * 8];
        bf16x8 pf1 = *(const bf16x8*)&plds[1][lr][lh * 8];
#pragma unroll
        for (int dt = 0; dt < 4; ++dt)
#pragma unroll
            for (int r = 0; r < 4; ++r) {
                o[dt][0][r] *= cc0;
                o[dt][1][r] *= cc1;
            }
#pragma unroll
        for (int dt = 0; dt < 4; ++dt) {
            o[dt][0] = mfma16(v[dt], pf0, o[dt][0]);
            o[dt][1] = mfma16(v[dt], pf1, o[dt][1]);
        }
    };

    bf16x8 kA[4], vA[4], kB[4], vB[4];
    LOADK(0, kA);
    LOADV(0, vA);
    int t = 0;
    while (true) {
        if (t + 1 < ntiles) { LOADK((t + 1) << 5, kB); LOADV((t + 1) << 5, vB); }
        PROCESS(t, kA, vA);
        if (++t >= ntiles) break;
        if (t + 1 < ntiles) { LOADK((t + 1) << 5, kA); LOADV((t + 1) << 5, vA); }
        PROCESS(t, kB, vB);
        if (++t >= ntiles) break;
    }

    int b = bh >> 4, h = bh & 15;
#pragma unroll
    for (int qt = 0; qt < 2; ++qt) {
        int qrow = (qt == 0) ? qrow0 : qrow1;
        float invl = 1.f / ((qt == 0) ? lreg0 : lreg1);
        float* yr = y + (size_t)(b * 2048 + qrow) * 1024 + h * 64;
#pragma unroll
        for (int dt = 0; dt < 4; ++dt) {
            float4 st;
            st.x = o[dt][qt][0] * invl;
            st.y = o[dt][qt][1] * invl;
            st.z = o[dt][qt][2] * invl;
            st.w = o[dt][qt][3] * invl;
            *(float4*)&yr[dt * 16 + lh * 4] = st;
        }
    }
}

extern "C" void kernel_launch(void* const* d_in, const int* in_sizes, int n_in,
                              void* d_out, int out_size, void* d_ws, size_t ws_size,
                              hipStream_t stream) {
    const float* x  = (const float*)d_in[0];
    const float* wq = (const float*)d_in[1];
    const float* wk = (const float*)d_in[2];
    const float* wv = (const float*)d_in[3];
    const float* wo = (const float*)d_in[4];
    const float* gq = (const float*)d_in[5];
    const float* gk = (const float*)d_in[6];
    const float* gv = (const float*)d_in[7];
    const float* go = (const float*)d_in[8];

    char* ws = (char*)d_ws;
    size_t off = 0;
    auto alloc = [&](size_t bytes) {
        size_t o = off;
        off += (bytes + 255) & ~(size_t)255;
        return o;
    };
    float* part = (float*)(ws + alloc(128 * 4));
    unsigned short* wbf = (unsigned short*)(ws + alloc(4ull * 1048576 * 2));   // 4 x [1024][1024] bf16
    unsigned short* abf = (unsigned short*)(ws + alloc(3ull * 4194304 * 2));   // 3 x [4096][1024] bf16
    float* asc = (float*)(ws + alloc(3ull * 4096 * 4));
    unsigned short* qbf = (unsigned short*)(ws + alloc(4194304ull * 2));       // [BH][T][D]
    unsigned short* kbf = (unsigned short*)(ws + alloc(4194304ull * 2));       // [BH][T][D]
    unsigned short* vtb = (unsigned short*)(ws + alloc(4194304ull * 2));       // [BH][D][T]
    float* ybuf = (float*)(ws + alloc(4194304ull * 4));                        // [B,T,C] f32
    unsigned short* ybf = (unsigned short*)(ws + alloc(4194304ull * 2));
    float* ysc = (float*)(ws + alloc(4096 * 4));
    (void)ws_size; (void)in_sizes; (void)n_in; (void)out_size;

    wabssum<<<128, 256, 0, stream>>>(wq, wk, wv, wo, part);
    wquant<<<256, 256, 0, stream>>>(wq, wk, wv, wo, part, wbf);
    actquant<3><<<4096, 256, 0, stream>>>(x, gq, gk, gv, abf, asc);
    gemm_qkv<<<dim3(32, 8, 3), 256, 0, stream>>>(abf, asc, wbf, part, qbf, kbf, vtb);
    attn<<<2048, 64, 0, stream>>>(qbf, kbf, vtb, ybuf);
    actquant<1><<<4096, 256, 0, stream>>>(ybuf, go, go, go, ybf, ysc);
    gemm_o<<<dim3(32, 8), 256, 0, stream>>>(ybf, ysc, wbf + 3 * 1048576, part + 96, (float*)d_out);
}

// Round 7
// 182.800 us; speedup vs baseline: 3.3150x; 1.0214x over previous
//
#include <hip/hip_runtime.h>
#include <hip/hip_bf16.h>

// B=2, T=2048, C=1024, H=16, D=64, M=B*T=4096
// All GEMMs: exact integer math via bf16 MFMA (ints <= 2^24 exact in fp32 accum).

typedef __attribute__((ext_vector_type(8))) short bf16x8;
typedef __attribute__((ext_vector_type(4))) float f32x4;

__device__ __forceinline__ f32x4 mfma16(bf16x8 a, bf16x8 b, f32x4 c) {
    return __builtin_amdgcn_mfma_f32_16x16x32_bf16(a, b, c, 0, 0, 0);
}

__device__ __forceinline__ unsigned short f2bf(float f) {
    unsigned int u = __float_as_uint(f);
    unsigned int r = (u + 0x7fffu + ((u >> 16) & 1u)) >> 16;
    return (unsigned short)r;
}

__device__ __forceinline__ unsigned int cvtpk_bf16(float lo, float hi) {
    unsigned int r;
    asm("v_cvt_pk_bf16_f32 %0, %1, %2" : "=v"(r) : "v"(lo), "v"(hi));
    return r;
}

__device__ __forceinline__ float exp2_fast(float x) {
    float r;
    asm("v_exp_f32 %0, %1" : "=v"(r) : "v"(x));
    return r;
}

__device__ __forceinline__ void gload_lds16(const unsigned short* g, unsigned short* l) {
    __builtin_amdgcn_global_load_lds((const __attribute__((address_space(1))) unsigned int*)g,
                                     (__attribute__((address_space(3))) unsigned int*)l, 16, 0, 0);
}

__device__ __forceinline__ float wredsum(float v) {
#pragma unroll
    for (int o = 32; o > 0; o >>= 1) v += __shfl_xor(v, o);
    return v;
}
__device__ __forceinline__ float wredmax(float v) {
#pragma unroll
    for (int o = 32; o > 0; o >>= 1) v = fmaxf(v, __shfl_xor(v, o));
    return v;
}

// ---------------- weight absmean partials (deterministic two-pass) ----------
__global__ __launch_bounds__(256) void wabssum(const float* __restrict__ w0, const float* __restrict__ w1,
                                               const float* __restrict__ w2, const float* __restrict__ w3,
                                               float* __restrict__ part) {
    int widx = blockIdx.x >> 5, b = blockIdx.x & 31;
    const float* w = (widx == 0) ? w0 : (widx == 1) ? w1 : (widx == 2) ? w2 : w3;
    const float4* w4 = (const float4*)w;
    int tid = threadIdx.x;
    float s = 0.f;
    int base = b * 8192 + tid;  // float4 units; 32 blocks * 8192 = 262144 = 1M floats
#pragma unroll
    for (int i = 0; i < 32; ++i) {
        float4 v = w4[base + i * 256];
        s += fabsf(v.x) + fabsf(v.y) + fabsf(v.z) + fabsf(v.w);
    }
    s = wredsum(s);
    __shared__ float red[4];
    int wid = tid >> 6, lid = tid & 63;
    if (lid == 0) red[wid] = s;
    __syncthreads();
    if (tid == 0) part[blockIdx.x] = red[0] + red[1] + red[2] + red[3];
}

// ---------------- ternary weight quant -> bf16 {-1,0,1} ---------------------
__global__ __launch_bounds__(256) void wquant(const float* __restrict__ w0, const float* __restrict__ w1,
                                              const float* __restrict__ w2, const float* __restrict__ w3,
                                              const float* __restrict__ part, unsigned short* __restrict__ wbf) {
    int widx = blockIdx.x >> 6, b = blockIdx.x & 63;
    const float* w = (widx == 0) ? w0 : (widx == 1) ? w1 : (widx == 2) ? w2 : w3;
    float s = 0.f;
#pragma unroll
    for (int i = 0; i < 32; ++i) s += part[widx * 32 + i];
    s = fmaxf(s * (1.f / 1048576.f), 1e-5f);
    float inv = 1.f / s;
    const float4* w4 = (const float4*)w;
    unsigned short* dst = wbf + (size_t)widx * 1048576;
    int tid = threadIdx.x;
#pragma unroll
    for (int it = 0; it < 16; ++it) {
        int i4 = b * 4096 + it * 256 + tid;
        float4 v = w4[i4];
        float q0 = fminf(fmaxf(rintf(v.x * inv), -1.f), 1.f);
        float q1 = fminf(fmaxf(rintf(v.y * inv), -1.f), 1.f);
        float q2 = fminf(fmaxf(rintf(v.z * inv), -1.f), 1.f);
        float q3 = fminf(fmaxf(rintf(v.w * inv), -1.f), 1.f);
        ((ushort4*)dst)[i4] = make_ushort4(f2bf(q0), f2bf(q1), f2bf(q2), f2bf(q3));
    }
}

// ------------- fused rmsnorm + per-token absmax quant (NP planes) -----------
template <int NP>
__global__ __launch_bounds__(256) void actquant(const float* __restrict__ x, const float* __restrict__ g0,
                                                const float* __restrict__ g1, const float* __restrict__ g2,
                                                unsigned short* __restrict__ aq, float* __restrict__ ascale) {
    int m = blockIdx.x, tid = threadIdx.x;
    int wid = tid >> 6, lid = tid & 63;
    __shared__ float red[4];
    float4 xv = ((const float4*)(x + (size_t)m * 1024))[tid];
    float ss = xv.x * xv.x + xv.y * xv.y + xv.z * xv.z + xv.w * xv.w;
    ss = wredsum(ss);
    if (lid == 0) red[wid] = ss;
    __syncthreads();
    float rstd = rsqrtf((red[0] + red[1] + red[2] + red[3]) * (1.f / 1024.f) + 1e-6f);
    const float* gs[3] = {g0, g1, g2};
#pragma unroll
    for (int p = 0; p < NP; ++p) {
        float4 gv = ((const float4*)gs[p])[tid];
        float a0 = xv.x * gv.x * rstd, a1 = xv.y * gv.y * rstd;
        float a2 = xv.z * gv.z * rstd, a3 = xv.w * gv.w * rstd;
        float am = fmaxf(fmaxf(fabsf(a0), fabsf(a1)), fmaxf(fabsf(a2), fabsf(a3)));
        am = wredmax(am);
        __syncthreads();  // protect red from previous use
        if (lid == 0) red[wid] = am;
        __syncthreads();
        float rm = fmaxf(fmaxf(red[0], red[1]), fmaxf(red[2], red[3]));
        float scale = 127.f / fmaxf(rm, 1e-5f);
        float q0 = fminf(fmaxf(rintf(a0 * scale), -128.f), 127.f);
        float q1 = fminf(fmaxf(rintf(a1 * scale), -128.f), 127.f);
        float q2 = fminf(fmaxf(rintf(a2 * scale), -128.f), 127.f);
        float q3 = fminf(fmaxf(rintf(a3 * scale), -128.f), 127.f);
        ((ushort4*)(aq + (size_t)p * 4194304 + (size_t)m * 1024))[tid] =
            make_ushort4(f2bf(q0), f2bf(q1), f2bf(q2), f2bf(q3));
        if (tid == 0) ascale[p * 4096 + m] = scale;
    }
}

// ------------- 128x128-tile GEMM core (m97 structure) -----------------------
// BK=64, 256 thr = 2x2 waves, 4x4 16x16 frags/wave, linear LDS + global_load_lds.
// MODE 0: out bf16 [B,H,T,D]; MODE 1: out bf16 [BH,D,T]; MODE 2: out f32 [M,N]
template <int MODE>
__device__ __forceinline__ void gemm_core(const unsigned short* __restrict__ A,
                                          const float* __restrict__ asc,
                                          const unsigned short* __restrict__ W, float s_w,
                                          void* __restrict__ outp, int bm, int bn,
                                          unsigned short* As, unsigned short* Bs) {
    int tid = threadIdx.x;
    int w = tid >> 6, l = tid & 63;
    int wr = w >> 1, wc = w & 1;
    int lr = l & 15, lh = l >> 4;
    f32x4 acc[4][4] = {};
    int srow = l >> 3;         // 0..7
    int scol = (l & 7) * 8;    // short offset
    const unsigned short* Ab = A + (size_t)(bm * 128) * 1024;
    const unsigned short* Wb = W + (size_t)(bn * 128) * 1024;

    for (int kt = 0; kt < 16; ++kt) {
        int k0 = kt * 64;
        __syncthreads();  // all waves done reading LDS from prev iter
#pragma unroll
        for (int j = 0; j < 4; ++j) {
            int c = j * 4 + w;  // 1KB chunk, wave-uniform LDS base
            gload_lds16(Ab + (size_t)(c * 8 + srow) * 1024 + k0 + scol, &As[c * 512]);
            gload_lds16(Wb + (size_t)(c * 8 + srow) * 1024 + k0 + scol, &Bs[c * 512]);
        }
        __syncthreads();  // vmcnt(0) drain + barrier: tile ready
#pragma unroll
        for (int ks = 0; ks < 2; ++ks) {
            int kb = ks * 32 + lh * 8;
            bf16x8 af[4], bfr[4];
#pragma unroll
            for (int mi = 0; mi < 4; ++mi) af[mi] = *(const bf16x8*)&As[(wr * 64 + mi * 16 + lr) * 64 + kb];
#pragma unroll
            for (int ni = 0; ni < 4; ++ni) bfr[ni] = *(const bf16x8*)&Bs[(wc * 64 + ni * 16 + lr) * 64 + kb];
#pragma unroll
            for (int mi = 0; mi < 4; ++mi)
#pragma unroll
                for (int ni = 0; ni < 4; ++ni) acc[mi][ni] = mfma16(af[mi], bfr[ni], acc[mi][ni]);
        }
    }
#pragma unroll
    for (int mi = 0; mi < 4; ++mi) {
        int mbase = bm * 128 + wr * 64 + mi * 16 + lh * 4;
#pragma unroll
        for (int ni = 0; ni < 4; ++ni) {
            int n = bn * 128 + wc * 64 + ni * 16 + lr;
            if (MODE == 1) {
                int b = mbase >> 11, t0 = mbase & 2047;
                int h = n >> 6, d = n & 63;
                ushort4 st;
                st.x = f2bf(acc[mi][ni][0] * s_w / asc[mbase + 0]);
                st.y = f2bf(acc[mi][ni][1] * s_w / asc[mbase + 1]);
                st.z = f2bf(acc[mi][ni][2] * s_w / asc[mbase + 2]);
                st.w = f2bf(acc[mi][ni][3] * s_w / asc[mbase + 3]);
                *(ushort4*)&((unsigned short*)outp)[(size_t)(b * 16 + h) * 131072 + (size_t)d * 2048 + t0] = st;
            } else {
#pragma unroll
                for (int i = 0; i < 4; ++i) {
                    int m = mbase + i;
                    float val = acc[mi][ni][i] * s_w / asc[m];
                    if (MODE == 0) {
                        int b = m >> 11, t = m & 2047, h = n >> 6, d = n & 63;
                        ((unsigned short*)outp)[(size_t)(b * 16 + h) * 131072 + (size_t)t * 64 + d] = f2bf(val);
                    } else {
                        ((float*)outp)[(size_t)m * 1024 + n] = val;
                    }
                }
            }
        }
    }
}

__device__ __forceinline__ float sw_from_part(const float* part) {
    float s = 0.f;
#pragma unroll
    for (int i = 0; i < 32; ++i) s += part[i];
    return fmaxf(s * (1.f / 1048576.f), 1e-5f);
}

// fused Q/K/V projection: blockIdx.z picks the gemm (0=q,1=k,2=v)
__global__ __launch_bounds__(256) void gemm_qkv(const unsigned short* __restrict__ abf,
                                                const float* __restrict__ ascale,
                                                const unsigned short* __restrict__ wbf,
                                                const float* __restrict__ part,
                                                unsigned short* __restrict__ qbf,
                                                unsigned short* __restrict__ kbf,
                                                unsigned short* __restrict__ vtb) {
    __shared__ alignas(16) unsigned short As[8192];
    __shared__ alignas(16) unsigned short Bs[8192];
    int z = blockIdx.z;
    const unsigned short* A = abf + (size_t)z * 4194304;
    const float* asc = ascale + z * 4096;
    const unsigned short* W = wbf + (size_t)z * 1048576;
    float s_w = sw_from_part(part + z * 32);
    int bm = blockIdx.x, bn = blockIdx.y;
    if (z == 0) {
        gemm_core<0>(A, asc, W, s_w, qbf, bm, bn, As, Bs);
    } else if (z == 1) {
        gemm_core<0>(A, asc, W, s_w, kbf, bm, bn, As, Bs);
    } else {
        gemm_core<1>(A, asc, W, s_w, vtb, bm, bn, As, Bs);
    }
}

// output projection: f32 out
__global__ __launch_bounds__(256) void gemm_o(const unsigned short* __restrict__ A,
                                              const float* __restrict__ asc,
                                              const unsigned short* __restrict__ W,
                                              const float* __restrict__ part, float* __restrict__ outp) {
    __shared__ alignas(16) unsigned short As[8192];
    __shared__ alignas(16) unsigned short Bs[8192];
    float s_w = sw_from_part(part);
    gemm_core<2>(A, asc, W, s_w, outp, blockIdx.x, blockIdx.y, As, Bs);
}

// ---------------- flash attention (causal, 16 heads, D=64) ------------------
// 1 wave/block, 32 q-rows/wave (two 16-row fragments sharing one K/V stream).
// Swapped QK^T (S^T = mfma(K,Q)) -> per-lane in-register softmax in exp2
// domain (v_exp_f32 = 2^x). Causal mask applied only on the diagonal tile
// (t==c); defer-max (T13, log2-THR=11) skips the O-rescale on most tiles;
// s_setprio(1) around MFMA clusters (T5). Heavy chunks dispatched first.
__global__ __launch_bounds__(64) void attn(const unsigned short* __restrict__ qb,
                                           const unsigned short* __restrict__ kb,
                                           const unsigned short* __restrict__ vt, float* __restrict__ y) {
    int blk = blockIdx.x;
    int bh = blk & 31;
    int c = 63 - (blk >> 5);  // 32-row chunk 0..63, heaviest first
    int q0 = c << 5;
    int l = threadIdx.x & 63;
    int lr = l & 15, lh = l >> 4;
    const unsigned short* qbase = qb + (size_t)bh * 131072;
    const unsigned short* kbase = kb + (size_t)bh * 131072;
    const unsigned short* vbase = vt + (size_t)bh * 131072;

    // Q fragments: qf[qt][ks], q-row = q0 + qt*16 + lr
    bf16x8 qf00 = *(const bf16x8*)&qbase[(size_t)(q0 + lr) * 64 + lh * 8];
    bf16x8 qf01 = *(const bf16x8*)&qbase[(size_t)(q0 + lr) * 64 + 32 + lh * 8];
    bf16x8 qf10 = *(const bf16x8*)&qbase[(size_t)(q0 + 16 + lr) * 64 + lh * 8];
    bf16x8 qf11 = *(const bf16x8*)&qbase[(size_t)(q0 + 16 + lr) * 64 + 32 + lh * 8];

    f32x4 o[4][2] = {};  // [dt][qt]
    const float ninf = -__builtin_inff();
    const float SC = 0.125f * 1.44269504f;  // 1/sqrt(64) * log2(e)
    float mreg0 = ninf, mreg1 = ninf;       // running max (log2 domain)
    float lreg0 = 0.f, lreg1 = 0.f;
    __shared__ alignas(16) unsigned short plds[2][16][40];

    int qrow0 = q0 + lr, qrow1 = q0 + 16 + lr;
    int ntiles = c + 1;

    auto LOADK = [&](int kv0, bf16x8* k) {
        k[0] = *(const bf16x8*)&kbase[(size_t)(kv0 + lr) * 64 + lh * 8];
        k[1] = *(const bf16x8*)&kbase[(size_t)(kv0 + lr) * 64 + 32 + lh * 8];
        k[2] = *(const bf16x8*)&kbase[(size_t)(kv0 + 16 + lr) * 64 + lh * 8];
        k[3] = *(const bf16x8*)&kbase[(size_t)(kv0 + 16 + lr) * 64 + 32 + lh * 8];
    };
    auto LOADV = [&](int kv0, bf16x8* v) {
        v[0] = *(const bf16x8*)&vbase[(size_t)(lr)*2048 + kv0 + lh * 8];
        v[1] = *(const bf16x8*)&vbase[(size_t)(16 + lr) * 2048 + kv0 + lh * 8];
        v[2] = *(const bf16x8*)&vbase[(size_t)(32 + lr) * 2048 + kv0 + lh * 8];
        v[3] = *(const bf16x8*)&vbase[(size_t)(48 + lr) * 2048 + kv0 + lh * 8];
    };
    auto PROCESS = [&](int t, bf16x8* k, bf16x8* v) {
        int kv0 = t << 5;
        __builtin_amdgcn_s_setprio(1);
        f32x4 s00 = {}, s01 = {}, s10 = {}, s11 = {};
        s00 = mfma16(k[0], qf00, s00);
        s00 = mfma16(k[1], qf01, s00);
        s01 = mfma16(k[2], qf00, s01);
        s01 = mfma16(k[3], qf01, s01);
        s10 = mfma16(k[0], qf10, s10);
        s10 = mfma16(k[1], qf11, s10);
        s11 = mfma16(k[2], qf10, s11);
        s11 = mfma16(k[3], qf11, s11);
        __builtin_amdgcn_s_setprio(0);
        // s00[r] = S[q0+lr][kv0+lh*4+r], s01[r] = S[q0+lr][kv0+16+lh*4+r], etc.
        float p0[8], p1[8];
        if (t == c) {  // diagonal tile: apply causal mask
#pragma unroll
            for (int r = 0; r < 4; ++r) {
                int kva = kv0 + lh * 4 + r, kvb = kv0 + 16 + lh * 4 + r;
                p0[r]     = (kva <= qrow0) ? s00[r] * SC : ninf;
                p0[r + 4] = (kvb <= qrow0) ? s01[r] * SC : ninf;
                p1[r]     = (kva <= qrow1) ? s10[r] * SC : ninf;
                p1[r + 4] = (kvb <= qrow1) ? s11[r] * SC : ninf;
            }
        } else {  // fully-valid tile: no mask
#pragma unroll
            for (int r = 0; r < 4; ++r) {
                p0[r] = s00[r] * SC;
                p0[r + 4] = s01[r] * SC;
                p1[r] = s10[r] * SC;
                p1[r + 4] = s11[r] * SC;
            }
        }
        float t0 = fmaxf(fmaxf(fmaxf(p0[0], p0[1]), fmaxf(p0[2], p0[3])),
                         fmaxf(fmaxf(p0[4], p0[5]), fmaxf(p0[6], p0[7])));
        float t1 = fmaxf(fmaxf(fmaxf(p1[0], p1[1]), fmaxf(p1[2], p1[3])),
                         fmaxf(fmaxf(p1[4], p1[5]), fmaxf(p1[6], p1[7])));
        t0 = fmaxf(t0, __shfl_xor(t0, 16));
        t0 = fmaxf(t0, __shfl_xor(t0, 32));
        t1 = fmaxf(t1, __shfl_xor(t1, 16));
        t1 = fmaxf(t1, __shfl_xor(t1, 32));
        // defer-max: rescale only when a row max grew past THR (log2 domain)
        if (__any((t0 > mreg0 + 11.f) || (t1 > mreg1 + 11.f))) {
            float mn0 = fmaxf(mreg0, t0), mn1 = fmaxf(mreg1, t1);
            float cc0 = exp2_fast(mreg0 - mn0), cc1 = exp2_fast(mreg1 - mn1);
            lreg0 *= cc0;
            lreg1 *= cc1;
            mreg0 = mn0;
            mreg1 = mn1;
#pragma unroll
            for (int dt = 0; dt < 4; ++dt)
#pragma unroll
                for (int r = 0; r < 4; ++r) {
                    o[dt][0][r] *= cc0;
                    o[dt][1][r] *= cc1;
                }
        }
        float ps0[8], ps1[8];
#pragma unroll
        for (int r = 0; r < 8; ++r) {
            ps0[r] = exp2_fast(p0[r] - mreg0);
            ps1[r] = exp2_fast(p1[r] - mreg1);
        }
        float sum0 = ((ps0[0] + ps0[1]) + (ps0[2] + ps0[3])) + ((ps0[4] + ps0[5]) + (ps0[6] + ps0[7]));
        float sum1 = ((ps1[0] + ps1[1]) + (ps1[2] + ps1[3])) + ((ps1[4] + ps1[5]) + (ps1[6] + ps1[7]));
        sum0 += __shfl_xor(sum0, 16);
        sum0 += __shfl_xor(sum0, 32);
        sum1 += __shfl_xor(sum1, 16);
        sum1 += __shfl_xor(sum1, 32);
        lreg0 += sum0;
        lreg1 += sum1;
        // pack + store P^T via LDS: plds[qt][q=lr][kv_rel]
        uint2 w0lo, w0hi, w1lo, w1hi;
        w0lo.x = cvtpk_bf16(ps0[0], ps0[1]);
        w0lo.y = cvtpk_bf16(ps0[2], ps0[3]);
        w0hi.x = cvtpk_bf16(ps0[4], ps0[5]);
        w0hi.y = cvtpk_bf16(ps0[6], ps0[7]);
        w1lo.x = cvtpk_bf16(ps1[0], ps1[1]);
        w1lo.y = cvtpk_bf16(ps1[2], ps1[3]);
        w1hi.x = cvtpk_bf16(ps1[4], ps1[5]);
        w1hi.y = cvtpk_bf16(ps1[6], ps1[7]);
        *(uint2*)&plds[0][lr][lh * 4] = w0lo;
        *(uint2*)&plds[0][lr][16 + lh * 4] = w0hi;
        *(uint2*)&plds[1][lr][lh * 4] = w1lo;
        *(uint2*)&plds[1][lr][16 + lh * 4] = w1hi;
        bf16x8 pf0 = *(const bf16x8*)&plds[0][lr][lh * 8];
        bf16x8 pf1 = *(const bf16x8*)&plds[1][lr][lh * 8];
        __builtin_amdgcn_s_setprio(1);
#pragma unroll
        for (int dt = 0; dt < 4; ++dt) {
            o[dt][0] = mfma16(v[dt], pf0, o[dt][0]);
            o[dt][1] = mfma16(v[dt], pf1, o[dt][1]);
        }
        __builtin_amdgcn_s_setprio(0);
    };

    bf16x8 kA[4], vA[4], kB[4], vB[4];
    LOADK(0, kA);
    LOADV(0, vA);
    int t = 0;
    while (true) {
        if (t + 1 < ntiles) { LOADK((t + 1) << 5, kB); LOADV((t + 1) << 5, vB); }
        PROCESS(t, kA, vA);
        if (++t >= ntiles) break;
        if (t + 1 < ntiles) { LOADK((t + 1) << 5, kA); LOADV((t + 1) << 5, vA); }
        PROCESS(t, kB, vB);
        if (++t >= ntiles) break;
    }

    int b = bh >> 4, h = bh & 15;
#pragma unroll
    for (int qt = 0; qt < 2; ++qt) {
        int qrow = (qt == 0) ? qrow0 : qrow1;
        float invl = 1.f / ((qt == 0) ? lreg0 : lreg1);
        float* yr = y + (size_t)(b * 2048 + qrow) * 1024 + h * 64;
#pragma unroll
        for (int dt = 0; dt < 4; ++dt) {
            float4 st;
            st.x = o[dt][qt][0] * invl;
            st.y = o[dt][qt][1] * invl;
            st.z = o[dt][qt][2] * invl;
            st.w = o[dt][qt][3] * invl;
            *(float4*)&yr[dt * 16 + lh * 4] = st;
        }
    }
}

extern "C" void kernel_launch(void* const* d_in, const int* in_sizes, int n_in,
                              void* d_out, int out_size, void* d_ws, size_t ws_size,
                              hipStream_t stream) {
    const float* x  = (const float*)d_in[0];
    const float* wq = (const float*)d_in[1];
    const float* wk = (const float*)d_in[2];
    const float* wv = (const float*)d_in[3];
    const float* wo = (const float*)d_in[4];
    const float* gq = (const float*)d_in[5];
    const float* gk = (const float*)d_in[6];
    const float* gv = (const float*)d_in[7];
    const float* go = (const float*)d_in[8];

    char* ws = (char*)d_ws;
    size_t off = 0;
    auto alloc = [&](size_t bytes) {
        size_t o = off;
        off += (bytes + 255) & ~(size_t)255;
        return o;
    };
    float* part = (float*)(ws + alloc(128 * 4));
    unsigned short* wbf = (unsigned short*)(ws + alloc(4ull * 1048576 * 2));   // 4 x [1024][1024] bf16
    unsigned short* abf = (unsigned short*)(ws + alloc(3ull * 4194304 * 2));   // 3 x [4096][1024] bf16
    float* asc = (float*)(ws + alloc(3ull * 4096 * 4));
    unsigned short* qbf = (unsigned short*)(ws + alloc(4194304ull * 2));       // [BH][T][D]
    unsigned short* kbf = (unsigned short*)(ws + alloc(4194304ull * 2));       // [BH][T][D]
    unsigned short* vtb = (unsigned short*)(ws + alloc(4194304ull * 2));       // [BH][D][T]
    float* ybuf = (float*)(ws + alloc(4194304ull * 4));                        // [B,T,C] f32
    unsigned short* ybf = (unsigned short*)(ws + alloc(4194304ull * 2));
    float* ysc = (float*)(ws + alloc(4096 * 4));
    (void)ws_size; (void)in_sizes; (void)n_in; (void)out_size;

    wabssum<<<128, 256, 0, stream>>>(wq, wk, wv, wo, part);
    wquant<<<256, 256, 0, stream>>>(wq, wk, wv, wo, part, wbf);
    actquant<3><<<4096, 256, 0, stream>>>(x, gq, gk, gv, abf, asc);
    gemm_qkv<<<dim3(32, 8, 3), 256, 0, stream>>>(abf, asc, wbf, part, qbf, kbf, vtb);
    attn<<<2048, 64, 0, stream>>>(qbf, kbf, vtb, ybuf);
    actquant<1><<<4096, 256, 0, stream>>>(ybuf, go, go, go, ybf, ysc);
    gemm_o<<<dim3(32, 8), 256, 0, stream>>>(ybf, ysc, wbf + 3 * 1048576, part + 96, (float*)d_out);
}

// Round 8
// 176.530 us; speedup vs baseline: 3.4327x; 1.0355x over previous
//
#include <hip/hip_runtime.h>
#include <hip/hip_bf16.h>

// B=2, T=2048, C=1024, H=16, D=64, M=B*T=4096
// All GEMMs: exact integer math via bf16 MFMA (ints <= 2^24 exact in fp32 accum).

typedef __attribute__((ext_vector_type(8))) short bf16x8;
typedef __attribute__((ext_vector_type(4))) float f32x4;

__device__ __forceinline__ f32x4 mfma16(bf16x8 a, bf16x8 b, f32x4 c) {
    return __builtin_amdgcn_mfma_f32_16x16x32_bf16(a, b, c, 0, 0, 0);
}

__device__ __forceinline__ unsigned short f2bf(float f) {
    unsigned int u = __float_as_uint(f);
    unsigned int r = (u + 0x7fffu + ((u >> 16) & 1u)) >> 16;
    return (unsigned short)r;
}

__device__ __forceinline__ unsigned int cvtpk_bf16(float lo, float hi) {
    unsigned int r;
    asm("v_cvt_pk_bf16_f32 %0, %1, %2" : "=v"(r) : "v"(lo), "v"(hi));
    return r;
}

__device__ __forceinline__ float exp2_fast(float x) {
    float r;
    asm("v_exp_f32 %0, %1" : "=v"(r) : "v"(x));
    return r;
}

__device__ __forceinline__ void gload_lds16(const unsigned short* g, unsigned short* l) {
    __builtin_amdgcn_global_load_lds((const __attribute__((address_space(1))) unsigned int*)g,
                                     (__attribute__((address_space(3))) unsigned int*)l, 16, 0, 0);
}

__device__ __forceinline__ float wredsum(float v) {
#pragma unroll
    for (int o = 32; o > 0; o >>= 1) v += __shfl_xor(v, o);
    return v;
}
__device__ __forceinline__ float wredmax(float v) {
#pragma unroll
    for (int o = 32; o > 0; o >>= 1) v = fmaxf(v, __shfl_xor(v, o));
    return v;
}

// ---------------- weight absmean partials (deterministic two-pass) ----------
__global__ __launch_bounds__(256) void wabssum(const float* __restrict__ w0, const float* __restrict__ w1,
                                               const float* __restrict__ w2, const float* __restrict__ w3,
                                               float* __restrict__ part) {
    int widx = blockIdx.x >> 5, b = blockIdx.x & 31;
    const float* w = (widx == 0) ? w0 : (widx == 1) ? w1 : (widx == 2) ? w2 : w3;
    const float4* w4 = (const float4*)w;
    int tid = threadIdx.x;
    float s = 0.f;
    int base = b * 8192 + tid;  // float4 units; 32 blocks * 8192 = 262144 = 1M floats
#pragma unroll
    for (int i = 0; i < 32; ++i) {
        float4 v = w4[base + i * 256];
        s += fabsf(v.x) + fabsf(v.y) + fabsf(v.z) + fabsf(v.w);
    }
    s = wredsum(s);
    __shared__ float red[4];
    int wid = tid >> 6, lid = tid & 63;
    if (lid == 0) red[wid] = s;
    __syncthreads();
    if (tid == 0) part[blockIdx.x] = red[0] + red[1] + red[2] + red[3];
}

// ---------------- ternary weight quant -> bf16 {-1,0,1} ---------------------
__global__ __launch_bounds__(256) void wquant(const float* __restrict__ w0, const float* __restrict__ w1,
                                              const float* __restrict__ w2, const float* __restrict__ w3,
                                              const float* __restrict__ part, unsigned short* __restrict__ wbf) {
    int widx = blockIdx.x >> 6, b = blockIdx.x & 63;
    const float* w = (widx == 0) ? w0 : (widx == 1) ? w1 : (widx == 2) ? w2 : w3;
    float s = 0.f;
#pragma unroll
    for (int i = 0; i < 32; ++i) s += part[widx * 32 + i];
    s = fmaxf(s * (1.f / 1048576.f), 1e-5f);
    float inv = 1.f / s;
    const float4* w4 = (const float4*)w;
    unsigned short* dst = wbf + (size_t)widx * 1048576;
    int tid = threadIdx.x;
#pragma unroll
    for (int it = 0; it < 16; ++it) {
        int i4 = b * 4096 + it * 256 + tid;
        float4 v = w4[i4];
        float q0 = fminf(fmaxf(rintf(v.x * inv), -1.f), 1.f);
        float q1 = fminf(fmaxf(rintf(v.y * inv), -1.f), 1.f);
        float q2 = fminf(fmaxf(rintf(v.z * inv), -1.f), 1.f);
        float q3 = fminf(fmaxf(rintf(v.w * inv), -1.f), 1.f);
        ((ushort4*)dst)[i4] = make_ushort4(f2bf(q0), f2bf(q1), f2bf(q2), f2bf(q3));
    }
}

// ------------- fused rmsnorm + per-token absmax quant (NP planes) -----------
template <int NP>
__global__ __launch_bounds__(256) void actquant(const float* __restrict__ x, const float* __restrict__ g0,
                                                const float* __restrict__ g1, const float* __restrict__ g2,
                                                unsigned short* __restrict__ aq, float* __restrict__ ascale) {
    int m = blockIdx.x, tid = threadIdx.x;
    int wid = tid >> 6, lid = tid & 63;
    __shared__ float red[4];
    float4 xv = ((const float4*)(x + (size_t)m * 1024))[tid];
    float ss = xv.x * xv.x + xv.y * xv.y + xv.z * xv.z + xv.w * xv.w;
    ss = wredsum(ss);
    if (lid == 0) red[wid] = ss;
    __syncthreads();
    float rstd = rsqrtf((red[0] + red[1] + red[2] + red[3]) * (1.f / 1024.f) + 1e-6f);
    const float* gs[3] = {g0, g1, g2};
#pragma unroll
    for (int p = 0; p < NP; ++p) {
        float4 gv = ((const float4*)gs[p])[tid];
        float a0 = xv.x * gv.x * rstd, a1 = xv.y * gv.y * rstd;
        float a2 = xv.z * gv.z * rstd, a3 = xv.w * gv.w * rstd;
        float am = fmaxf(fmaxf(fabsf(a0), fabsf(a1)), fmaxf(fabsf(a2), fabsf(a3)));
        am = wredmax(am);
        __syncthreads();  // protect red from previous use
        if (lid == 0) red[wid] = am;
        __syncthreads();
        float rm = fmaxf(fmaxf(red[0], red[1]), fmaxf(red[2], red[3]));
        float scale = 127.f / fmaxf(rm, 1e-5f);
        float q0 = fminf(fmaxf(rintf(a0 * scale), -128.f), 127.f);
        float q1 = fminf(fmaxf(rintf(a1 * scale), -128.f), 127.f);
        float q2 = fminf(fmaxf(rintf(a2 * scale), -128.f), 127.f);
        float q3 = fminf(fmaxf(rintf(a3 * scale), -128.f), 127.f);
        ((ushort4*)(aq + (size_t)p * 4194304 + (size_t)m * 1024))[tid] =
            make_ushort4(f2bf(q0), f2bf(q1), f2bf(q2), f2bf(q3));
        if (tid == 0) ascale[p * 4096 + m] = scale;
    }
}

// ------------- 128x128-tile GEMM core (dbuf + XOR-swizzled LDS) -------------
// BK=64, 256 thr = 2x2 waves, 4x4 16x16 frags/wave.
// T3-minimal: double-buffered LDS, STAGE(t+1) issued BEFORE compute of t,
// single __syncthreads (vmcnt drain) per K-step.
// T2 rule-#21: global_load_lds writes linearly -> pre-swizzle the global
// SOURCE column (col ^= srow*8 shorts) and apply the same XOR on ds_read
// (kb ^= (lr&7)*8). LDS[r][c] = G[r][c ^ ((r&7)*8)]; 16-way conflict -> free.
// MODE 0: out bf16 [B,H,T,D]; MODE 1: out bf16 [BH,D,T]; MODE 2: out f32 [M,N]
template <int MODE>
__device__ __forceinline__ void gemm_core(const unsigned short* __restrict__ A,
                                          const float* __restrict__ asc,
                                          const unsigned short* __restrict__ W, float s_w,
                                          void* __restrict__ outp, int bm, int bn,
                                          unsigned short* As, unsigned short* Bs) {
    int tid = threadIdx.x;
    int w = tid >> 6, l = tid & 63;
    int wr = w >> 1, wc = w & 1;
    int lr = l & 15, lh = l >> 4;
    f32x4 acc[4][4] = {};
    int srow = l >> 3;                    // 0..7
    int scol = ((l & 7) ^ srow) * 8;      // pre-swizzled source col (shorts)
    int key8 = (lr & 7) * 8;              // read-side XOR key (shorts)
    const unsigned short* Ab = A + (size_t)(bm * 128) * 1024;
    const unsigned short* Wb = W + (size_t)(bn * 128) * 1024;

    auto STAGE = [&](int kt, int buf) {
        int k0 = kt * 64;
        unsigned short* Ad = As + buf * 8192;
        unsigned short* Bd = Bs + buf * 8192;
#pragma unroll
        for (int j = 0; j < 4; ++j) {
            int c = j * 4 + w;  // 1KB chunk, wave-uniform LDS base
            gload_lds16(Ab + (size_t)(c * 8 + srow) * 1024 + k0 + scol, Ad + c * 512);
            gload_lds16(Wb + (size_t)(c * 8 + srow) * 1024 + k0 + scol, Bd + c * 512);
        }
    };

    STAGE(0, 0);
    __syncthreads();  // vmcnt(0) drain: buf0 ready
    for (int kt = 0; kt < 16; ++kt) {
        int cur = kt & 1;
        if (kt < 15) STAGE(kt + 1, cur ^ 1);  // prefetch rides under compute
        const unsigned short* Ar = As + cur * 8192;
        const unsigned short* Br = Bs + cur * 8192;
#pragma unroll
        for (int ks = 0; ks < 2; ++ks) {
            int kb = (ks * 32 + lh * 8) ^ key8;
            bf16x8 af[4], bfr[4];
#pragma unroll
            for (int mi = 0; mi < 4; ++mi) af[mi] = *(const bf16x8*)&Ar[(wr * 64 + mi * 16 + lr) * 64 + kb];
#pragma unroll
            for (int ni = 0; ni < 4; ++ni) bfr[ni] = *(const bf16x8*)&Br[(wc * 64 + ni * 16 + lr) * 64 + kb];
#pragma unroll
            for (int mi = 0; mi < 4; ++mi)
#pragma unroll
                for (int ni = 0; ni < 4; ++ni) acc[mi][ni] = mfma16(af[mi], bfr[ni], acc[mi][ni]);
        }
        __syncthreads();  // drains prefetch (had full compute phase) + read/write fence
    }
#pragma unroll
    for (int mi = 0; mi < 4; ++mi) {
        int mbase = bm * 128 + wr * 64 + mi * 16 + lh * 4;
#pragma unroll
        for (int ni = 0; ni < 4; ++ni) {
            int n = bn * 128 + wc * 64 + ni * 16 + lr;
            if (MODE == 1) {
                int b = mbase >> 11, t0 = mbase & 2047;
                int h = n >> 6, d = n & 63;
                ushort4 st;
                st.x = f2bf(acc[mi][ni][0] * s_w / asc[mbase + 0]);
                st.y = f2bf(acc[mi][ni][1] * s_w / asc[mbase + 1]);
                st.z = f2bf(acc[mi][ni][2] * s_w / asc[mbase + 2]);
                st.w = f2bf(acc[mi][ni][3] * s_w / asc[mbase + 3]);
                *(ushort4*)&((unsigned short*)outp)[(size_t)(b * 16 + h) * 131072 + (size_t)d * 2048 + t0] = st;
            } else {
#pragma unroll
                for (int i = 0; i < 4; ++i) {
                    int m = mbase + i;
                    float val = acc[mi][ni][i] * s_w / asc[m];
                    if (MODE == 0) {
                        int b = m >> 11, t = m & 2047, h = n >> 6, d = n & 63;
                        ((unsigned short*)outp)[(size_t)(b * 16 + h) * 131072 + (size_t)t * 64 + d] = f2bf(val);
                    } else {
                        ((float*)outp)[(size_t)m * 1024 + n] = val;
                    }
                }
            }
        }
    }
}

__device__ __forceinline__ float sw_from_part(const float* part) {
    float s = 0.f;
#pragma unroll
    for (int i = 0; i < 32; ++i) s += part[i];
    return fmaxf(s * (1.f / 1048576.f), 1e-5f);
}

// fused Q/K/V projection: blockIdx.z picks the gemm (0=q,1=k,2=v)
__global__ __launch_bounds__(256) void gemm_qkv(const unsigned short* __restrict__ abf,
                                                const float* __restrict__ ascale,
                                                const unsigned short* __restrict__ wbf,
                                                const float* __restrict__ part,
                                                unsigned short* __restrict__ qbf,
                                                unsigned short* __restrict__ kbf,
                                                unsigned short* __restrict__ vtb) {
    __shared__ alignas(16) unsigned short As[16384];  // 2 x 8192 dbuf
    __shared__ alignas(16) unsigned short Bs[16384];
    int z = blockIdx.z;
    const unsigned short* A = abf + (size_t)z * 4194304;
    const float* asc = ascale + z * 4096;
    const unsigned short* W = wbf + (size_t)z * 1048576;
    float s_w = sw_from_part(part + z * 32);
    int bm = blockIdx.x, bn = blockIdx.y;
    if (z == 0) {
        gemm_core<0>(A, asc, W, s_w, qbf, bm, bn, As, Bs);
    } else if (z == 1) {
        gemm_core<0>(A, asc, W, s_w, kbf, bm, bn, As, Bs);
    } else {
        gemm_core<1>(A, asc, W, s_w, vtb, bm, bn, As, Bs);
    }
}

// output projection: f32 out
__global__ __launch_bounds__(256) void gemm_o(const unsigned short* __restrict__ A,
                                              const float* __restrict__ asc,
                                              const unsigned short* __restrict__ W,
                                              const float* __restrict__ part, float* __restrict__ outp) {
    __shared__ alignas(16) unsigned short As[16384];
    __shared__ alignas(16) unsigned short Bs[16384];
    float s_w = sw_from_part(part);
    gemm_core<2>(A, asc, W, s_w, outp, blockIdx.x, blockIdx.y, As, Bs);
}

// ---------------- flash attention (causal, 16 heads, D=64) ------------------
// 1 wave/block, 32 q-rows/wave (two 16-row fragments sharing one K/V stream).
// Swapped QK^T (S^T = mfma(K,Q)) -> per-lane in-register softmax in exp2
// domain (v_exp_f32 = 2^x). Causal mask applied only on the diagonal tile
// (t==c); defer-max (T13, log2-THR=11) skips the O-rescale on most tiles;
// s_setprio(1) around MFMA clusters (T5). Heavy chunks dispatched first.
__global__ __launch_bounds__(64) void attn(const unsigned short* __restrict__ qb,
                                           const unsigned short* __restrict__ kb,
                                           const unsigned short* __restrict__ vt, float* __restrict__ y) {
    int blk = blockIdx.x;
    int bh = blk & 31;
    int c = 63 - (blk >> 5);  // 32-row chunk 0..63, heaviest first
    int q0 = c << 5;
    int l = threadIdx.x & 63;
    int lr = l & 15, lh = l >> 4;
    const unsigned short* qbase = qb + (size_t)bh * 131072;
    const unsigned short* kbase = kb + (size_t)bh * 131072;
    const unsigned short* vbase = vt + (size_t)bh * 131072;

    // Q fragments: qf[qt][ks], q-row = q0 + qt*16 + lr
    bf16x8 qf00 = *(const bf16x8*)&qbase[(size_t)(q0 + lr) * 64 + lh * 8];
    bf16x8 qf01 = *(const bf16x8*)&qbase[(size_t)(q0 + lr) * 64 + 32 + lh * 8];
    bf16x8 qf10 = *(const bf16x8*)&qbase[(size_t)(q0 + 16 + lr) * 64 + lh * 8];
    bf16x8 qf11 = *(const bf16x8*)&qbase[(size_t)(q0 + 16 + lr) * 64 + 32 + lh * 8];

    f32x4 o[4][2] = {};  // [dt][qt]
    const float ninf = -__builtin_inff();
    const float SC = 0.125f * 1.44269504f;  // 1/sqrt(64) * log2(e)
    float mreg0 = ninf, mreg1 = ninf;       // running max (log2 domain)
    float lreg0 = 0.f, lreg1 = 0.f;
    __shared__ alignas(16) unsigned short plds[2][16][40];

    int qrow0 = q0 + lr, qrow1 = q0 + 16 + lr;
    int ntiles = c + 1;

    auto LOADK = [&](int kv0, bf16x8* k) {
        k[0] = *(const bf16x8*)&kbase[(size_t)(kv0 + lr) * 64 + lh * 8];
        k[1] = *(const bf16x8*)&kbase[(size_t)(kv0 + lr) * 64 + 32 + lh * 8];
        k[2] = *(const bf16x8*)&kbase[(size_t)(kv0 + 16 + lr) * 64 + lh * 8];
        k[3] = *(const bf16x8*)&kbase[(size_t)(kv0 + 16 + lr) * 64 + 32 + lh * 8];
    };
    auto LOADV = [&](int kv0, bf16x8* v) {
        v[0] = *(const bf16x8*)&vbase[(size_t)(lr)*2048 + kv0 + lh * 8];
        v[1] = *(const bf16x8*)&vbase[(size_t)(16 + lr) * 2048 + kv0 + lh * 8];
        v[2] = *(const bf16x8*)&vbase[(size_t)(32 + lr) * 2048 + kv0 + lh * 8];
        v[3] = *(const bf16x8*)&vbase[(size_t)(48 + lr) * 2048 + kv0 + lh * 8];
    };
    auto PROCESS = [&](int t, bf16x8* k, bf16x8* v) {
        int kv0 = t << 5;
        __builtin_amdgcn_s_setprio(1);
        f32x4 s00 = {}, s01 = {}, s10 = {}, s11 = {};
        s00 = mfma16(k[0], qf00, s00);
        s00 = mfma16(k[1], qf01, s00);
        s01 = mfma16(k[2], qf00, s01);
        s01 = mfma16(k[3], qf01, s01);
        s10 = mfma16(k[0], qf10, s10);
        s10 = mfma16(k[1], qf11, s10);
        s11 = mfma16(k[2], qf10, s11);
        s11 = mfma16(k[3], qf11, s11);
        __builtin_amdgcn_s_setprio(0);
        // s00[r] = S[q0+lr][kv0+lh*4+r], s01[r] = S[q0+lr][kv0+16+lh*4+r], etc.
        float p0[8], p1[8];
        if (t == c) {  // diagonal tile: apply causal mask
#pragma unroll
            for (int r = 0; r < 4; ++r) {
                int kva = kv0 + lh * 4 + r, kvb = kv0 + 16 + lh * 4 + r;
                p0[r]     = (kva <= qrow0) ? s00[r] * SC : ninf;
                p0[r + 4] = (kvb <= qrow0) ? s01[r] * SC : ninf;
                p1[r]     = (kva <= qrow1) ? s10[r] * SC : ninf;
                p1[r + 4] = (kvb <= qrow1) ? s11[r] * SC : ninf;
            }
        } else {  // fully-valid tile: no mask
#pragma unroll
            for (int r = 0; r < 4; ++r) {
                p0[r] = s00[r] * SC;
                p0[r + 4] = s01[r] * SC;
                p1[r] = s10[r] * SC;
                p1[r + 4] = s11[r] * SC;
            }
        }
        float t0 = fmaxf(fmaxf(fmaxf(p0[0], p0[1]), fmaxf(p0[2], p0[3])),
                         fmaxf(fmaxf(p0[4], p0[5]), fmaxf(p0[6], p0[7])));
        float t1 = fmaxf(fmaxf(fmaxf(p1[0], p1[1]), fmaxf(p1[2], p1[3])),
                         fmaxf(fmaxf(p1[4], p1[5]), fmaxf(p1[6], p1[7])));
        t0 = fmaxf(t0, __shfl_xor(t0, 16));
        t0 = fmaxf(t0, __shfl_xor(t0, 32));
        t1 = fmaxf(t1, __shfl_xor(t1, 16));
        t1 = fmaxf(t1, __shfl_xor(t1, 32));
        // defer-max: rescale only when a row max grew past THR (log2 domain)
        if (__any((t0 > mreg0 + 11.f) || (t1 > mreg1 + 11.f))) {
            float mn0 = fmaxf(mreg0, t0), mn1 = fmaxf(mreg1, t1);
            float cc0 = exp2_fast(mreg0 - mn0), cc1 = exp2_fast(mreg1 - mn1);
            lreg0 *= cc0;
            lreg1 *= cc1;
            mreg0 = mn0;
            mreg1 = mn1;
#pragma unroll
            for (int dt = 0; dt < 4; ++dt)
#pragma unroll
                for (int r = 0; r < 4; ++r) {
                    o[dt][0][r] *= cc0;
                    o[dt][1][r] *= cc1;
                }
        }
        float ps0[8], ps1[8];
#pragma unroll
        for (int r = 0; r < 8; ++r) {
            ps0[r] = exp2_fast(p0[r] - mreg0);
            ps1[r] = exp2_fast(p1[r] - mreg1);
        }
        float sum0 = ((ps0[0] + ps0[1]) + (ps0[2] + ps0[3])) + ((ps0[4] + ps0[5]) + (ps0[6] + ps0[7]));
        float sum1 = ((ps1[0] + ps1[1]) + (ps1[2] + ps1[3])) + ((ps1[4] + ps1[5]) + (ps1[6] + ps1[7]));
        sum0 += __shfl_xor(sum0, 16);
        sum0 += __shfl_xor(sum0, 32);
        sum1 += __shfl_xor(sum1, 16);
        sum1 += __shfl_xor(sum1, 32);
        lreg0 += sum0;
        lreg1 += sum1;
        // pack + store P^T via LDS: plds[qt][q=lr][kv_rel]
        uint2 w0lo, w0hi, w1lo, w1hi;
        w0lo.x = cvtpk_bf16(ps0[0], ps0[1]);
        w0lo.y = cvtpk_bf16(ps0[2], ps0[3]);
        w0hi.x = cvtpk_bf16(ps0[4], ps0[5]);
        w0hi.y = cvtpk_bf16(ps0[6], ps0[7]);
        w1lo.x = cvtpk_bf16(ps1[0], ps1[1]);
        w1lo.y = cvtpk_bf16(ps1[2], ps1[3]);
        w1hi.x = cvtpk_bf16(ps1[4], ps1[5]);
        w1hi.y = cvtpk_bf16(ps1[6], ps1[7]);
        *(uint2*)&plds[0][lr][lh * 4] = w0lo;
        *(uint2*)&plds[0][lr][16 + lh * 4] = w0hi;
        *(uint2*)&plds[1][lr][lh * 4] = w1lo;
        *(uint2*)&plds[1][lr][16 + lh * 4] = w1hi;
        bf16x8 pf0 = *(const bf16x8*)&plds[0][lr][lh * 8];
        bf16x8 pf1 = *(const bf16x8*)&plds[1][lr][lh * 8];
        __builtin_amdgcn_s_setprio(1);
#pragma unroll
        for (int dt = 0; dt < 4; ++dt) {
            o[dt][0] = mfma16(v[dt], pf0, o[dt][0]);
            o[dt][1] = mfma16(v[dt], pf1, o[dt][1]);
        }
        __builtin_amdgcn_s_setprio(0);
    };

    bf16x8 kA[4], vA[4], kB[4], vB[4];
    LOADK(0, kA);
    LOADV(0, vA);
    int t = 0;
    while (true) {
        if (t + 1 < ntiles) { LOADK((t + 1) << 5, kB); LOADV((t + 1) << 5, vB); }
        PROCESS(t, kA, vA);
        if (++t >= ntiles) break;
        if (t + 1 < ntiles) { LOADK((t + 1) << 5, kA); LOADV((t + 1) << 5, vA); }
        PROCESS(t, kB, vB);
        if (++t >= ntiles) break;
    }

    int b = bh >> 4, h = bh & 15;
#pragma unroll
    for (int qt = 0; qt < 2; ++qt) {
        int qrow = (qt == 0) ? qrow0 : qrow1;
        float invl = 1.f / ((qt == 0) ? lreg0 : lreg1);
        float* yr = y + (size_t)(b * 2048 + qrow) * 1024 + h * 64;
#pragma unroll
        for (int dt = 0; dt < 4; ++dt) {
            float4 st;
            st.x = o[dt][qt][0] * invl;
            st.y = o[dt][qt][1] * invl;
            st.z = o[dt][qt][2] * invl;
            st.w = o[dt][qt][3] * invl;
            *(float4*)&yr[dt * 16 + lh * 4] = st;
        }
    }
}

extern "C" void kernel_launch(void* const* d_in, const int* in_sizes, int n_in,
                              void* d_out, int out_size, void* d_ws, size_t ws_size,
                              hipStream_t stream) {
    const float* x  = (const float*)d_in[0];
    const float* wq = (const float*)d_in[1];
    const float* wk = (const float*)d_in[2];
    const float* wv = (const float*)d_in[3];
    const float* wo = (const float*)d_in[4];
    const float* gq = (const float*)d_in[5];
    const float* gk = (const float*)d_in[6];
    const float* gv = (const float*)d_in[7];
    const float* go = (const float*)d_in[8];

    char* ws = (char*)d_ws;
    size_t off = 0;
    auto alloc = [&](size_t bytes) {
        size_t o = off;
        off += (bytes + 255) & ~(size_t)255;
        return o;
    };
    float* part = (float*)(ws + alloc(128 * 4));
    unsigned short* wbf = (unsigned short*)(ws + alloc(4ull * 1048576 * 2));   // 4 x [1024][1024] bf16
    unsigned short* abf = (unsigned short*)(ws + alloc(3ull * 4194304 * 2));   // 3 x [4096][1024] bf16
    float* asc = (float*)(ws + alloc(3ull * 4096 * 4));
    unsigned short* qbf = (unsigned short*)(ws + alloc(4194304ull * 2));       // [BH][T][D]
    unsigned short* kbf = (unsigned short*)(ws + alloc(4194304ull * 2));       // [BH][T][D]
    unsigned short* vtb = (unsigned short*)(ws + alloc(4194304ull * 2));       // [BH][D][T]
    float* ybuf = (float*)(ws + alloc(4194304ull * 4));                        // [B,T,C] f32
    unsigned short* ybf = (unsigned short*)(ws + alloc(4194304ull * 2));
    float* ysc = (float*)(ws + alloc(4096 * 4));
    (void)ws_size; (void)in_sizes; (void)n_in; (void)out_size;

    wabssum<<<128, 256, 0, stream>>>(wq, wk, wv, wo, part);
    wquant<<<256, 256, 0, stream>>>(wq, wk, wv, wo, part, wbf);
    actquant<3><<<4096, 256, 0, stream>>>(x, gq, gk, gv, abf, asc);
    gemm_qkv<<<dim3(32, 8, 3), 256, 0, stream>>>(abf, asc, wbf, part, qbf, kbf, vtb);
    attn<<<2048, 64, 0, stream>>>(qbf, kbf, vtb, ybuf);
    actquant<1><<<4096, 256, 0, stream>>>(ybuf, go, go, go, ybf, ysc);
    gemm_o<<<dim3(32, 8), 256, 0, stream>>>(ybf, ysc, wbf + 3 * 1048576, part + 96, (float*)d_out);
}

// Round 9
// 144.606 us; speedup vs baseline: 4.1905x; 1.2208x over previous
//
#include <hip/hip_runtime.h>
#include <hip/hip_bf16.h>

// B=2, T=2048, C=1024, H=16, D=64, M=B*T=4096
// GEMMs: exact integer math via i8 MFMA (i32 accum, |dot| <= 130K exact).

typedef __attribute__((ext_vector_type(8))) short bf16x8;
typedef __attribute__((ext_vector_type(4))) float f32x4;
typedef __attribute__((ext_vector_type(4))) int i32x4;

__device__ __forceinline__ f32x4 mfma16(bf16x8 a, bf16x8 b, f32x4 c) {
    return __builtin_amdgcn_mfma_f32_16x16x32_bf16(a, b, c, 0, 0, 0);
}

__device__ __forceinline__ i32x4 mfma_i8(i32x4 a, i32x4 b, i32x4 c) {
    return __builtin_amdgcn_mfma_i32_16x16x64_i8(a, b, c, 0, 0, 0);
}

__device__ __forceinline__ unsigned short f2bf(float f) {
    unsigned int u = __float_as_uint(f);
    unsigned int r = (u + 0x7fffu + ((u >> 16) & 1u)) >> 16;
    return (unsigned short)r;
}

__device__ __forceinline__ unsigned int cvtpk_bf16(float lo, float hi) {
    unsigned int r;
    asm("v_cvt_pk_bf16_f32 %0, %1, %2" : "=v"(r) : "v"(lo), "v"(hi));
    return r;
}

__device__ __forceinline__ float exp2_fast(float x) {
    float r;
    asm("v_exp_f32 %0, %1" : "=v"(r) : "v"(x));
    return r;
}

__device__ __forceinline__ void gload_lds16(const void* g, void* l) {
    __builtin_amdgcn_global_load_lds((const __attribute__((address_space(1))) unsigned int*)g,
                                     (__attribute__((address_space(3))) unsigned int*)l, 16, 0, 0);
}

__device__ __forceinline__ int pack4i8(float a, float b, float c, float d) {
    unsigned int u = ((unsigned int)((int)a & 255)) | (((unsigned int)((int)b & 255)) << 8) |
                     (((unsigned int)((int)c & 255)) << 16) | (((unsigned int)((int)d & 255)) << 24);
    return (int)u;
}

__device__ __forceinline__ float wredsum(float v) {
#pragma unroll
    for (int o = 32; o > 0; o >>= 1) v += __shfl_xor(v, o);
    return v;
}
__device__ __forceinline__ float wredmax(float v) {
#pragma unroll
    for (int o = 32; o > 0; o >>= 1) v = fmaxf(v, __shfl_xor(v, o));
    return v;
}

// ---------------- weight absmean partials (deterministic two-pass) ----------
__global__ __launch_bounds__(256) void wabssum(const float* __restrict__ w0, const float* __restrict__ w1,
                                               const float* __restrict__ w2, const float* __restrict__ w3,
                                               float* __restrict__ part) {
    int widx = blockIdx.x >> 5, b = blockIdx.x & 31;
    const float* w = (widx == 0) ? w0 : (widx == 1) ? w1 : (widx == 2) ? w2 : w3;
    const float4* w4 = (const float4*)w;
    int tid = threadIdx.x;
    float s = 0.f;
    int base = b * 8192 + tid;
#pragma unroll
    for (int i = 0; i < 32; ++i) {
        float4 v = w4[base + i * 256];
        s += fabsf(v.x) + fabsf(v.y) + fabsf(v.z) + fabsf(v.w);
    }
    s = wredsum(s);
    __shared__ float red[4];
    int wid = tid >> 6, lid = tid & 63;
    if (lid == 0) red[wid] = s;
    __syncthreads();
    if (tid == 0) part[blockIdx.x] = red[0] + red[1] + red[2] + red[3];
}

// ---------------- ternary weight quant -> i8 {-1,0,1} -----------------------
__global__ __launch_bounds__(256) void wquant(const float* __restrict__ w0, const float* __restrict__ w1,
                                              const float* __restrict__ w2, const float* __restrict__ w3,
                                              const float* __restrict__ part, signed char* __restrict__ wq8) {
    int widx = blockIdx.x >> 6, b = blockIdx.x & 63;
    const float* w = (widx == 0) ? w0 : (widx == 1) ? w1 : (widx == 2) ? w2 : w3;
    float s = 0.f;
#pragma unroll
    for (int i = 0; i < 32; ++i) s += part[widx * 32 + i];
    s = fmaxf(s * (1.f / 1048576.f), 1e-5f);
    float inv = 1.f / s;
    const float4* w4 = (const float4*)w;
    int* dst = (int*)(wq8 + (size_t)widx * 1048576);
    int tid = threadIdx.x;
#pragma unroll
    for (int it = 0; it < 16; ++it) {
        int i4 = b * 4096 + it * 256 + tid;
        float4 v = w4[i4];
        float q0 = fminf(fmaxf(rintf(v.x * inv), -1.f), 1.f);
        float q1 = fminf(fmaxf(rintf(v.y * inv), -1.f), 1.f);
        float q2 = fminf(fmaxf(rintf(v.z * inv), -1.f), 1.f);
        float q3 = fminf(fmaxf(rintf(v.w * inv), -1.f), 1.f);
        dst[i4] = pack4i8(q0, q1, q2, q3);
    }
}

// ------------- fused rmsnorm + per-token absmax quant -> i8 (NP planes) -----
template <int NP>
__global__ __launch_bounds__(256) void actquant(const float* __restrict__ x, const float* __restrict__ g0,
                                                const float* __restrict__ g1, const float* __restrict__ g2,
                                                signed char* __restrict__ aq, float* __restrict__ ascale) {
    int m = blockIdx.x, tid = threadIdx.x;
    int wid = tid >> 6, lid = tid & 63;
    __shared__ float red[4];
    float4 xv = ((const float4*)(x + (size_t)m * 1024))[tid];
    float ss = xv.x * xv.x + xv.y * xv.y + xv.z * xv.z + xv.w * xv.w;
    ss = wredsum(ss);
    if (lid == 0) red[wid] = ss;
    __syncthreads();
    float rstd = rsqrtf((red[0] + red[1] + red[2] + red[3]) * (1.f / 1024.f) + 1e-6f);
    const float* gs[3] = {g0, g1, g2};
#pragma unroll
    for (int p = 0; p < NP; ++p) {
        float4 gv = ((const float4*)gs[p])[tid];
        float a0 = xv.x * gv.x * rstd, a1 = xv.y * gv.y * rstd;
        float a2 = xv.z * gv.z * rstd, a3 = xv.w * gv.w * rstd;
        float am = fmaxf(fmaxf(fabsf(a0), fabsf(a1)), fmaxf(fabsf(a2), fabsf(a3)));
        am = wredmax(am);
        __syncthreads();
        if (lid == 0) red[wid] = am;
        __syncthreads();
        float rm = fmaxf(fmaxf(red[0], red[1]), fmaxf(red[2], red[3]));
        float scale = 127.f / fmaxf(rm, 1e-5f);
        float q0 = fminf(fmaxf(rintf(a0 * scale), -128.f), 127.f);
        float q1 = fminf(fmaxf(rintf(a1 * scale), -128.f), 127.f);
        float q2 = fminf(fmaxf(rintf(a2 * scale), -128.f), 127.f);
        float q3 = fminf(fmaxf(rintf(a3 * scale), -128.f), 127.f);
        ((int*)(aq + (size_t)p * 4194304 + (size_t)m * 1024))[tid] = pack4i8(q0, q1, q2, q3);
        if (tid == 0) ascale[p * 4096 + m] = scale;
    }
}

// ------------- 128x128-tile i8 GEMM core (dbuf + XOR-swizzled LDS) ----------
// BK=128 i8, 256 thr = 2x2 waves, 4x4 16x16 frags/wave, K=1024 -> 8 steps.
// mfma_i32_16x16x64_i8: lane l holds row l&15, K-bytes (l>>4)*16..+15
// (extension of the verified bf16 16x16x32 mapping; C/D layout dtype-indep).
// T2 rule-#21 swizzle: pre-swizzled global source chunk + same XOR on read.
// MODE 0: out bf16 [B,H,T,D]; MODE 1: out bf16 [BH,D,T]; MODE 2: out f32 [M,N]
template <int MODE>
__device__ __forceinline__ void gemm_core(const signed char* __restrict__ A,
                                          const float* __restrict__ asc,
                                          const signed char* __restrict__ W, float s_w,
                                          void* __restrict__ outp, int bm, int bn,
                                          char* As, char* Bs) {
    int tid = threadIdx.x;
    int w = tid >> 6, l = tid & 63;
    int wr = w >> 1, wc = w & 1;
    int lr = l & 15, lh = l >> 4;
    i32x4 acc[4][4] = {};
    int srow = l >> 3;                    // 0..7
    int scolb = (((l & 7) ^ srow)) * 16;  // pre-swizzled source col (bytes)
    int key16 = (lr & 7) * 16;            // read-side XOR key (bytes)
    const signed char* Ab = A + (size_t)(bm * 128) * 1024;
    const signed char* Wb = W + (size_t)(bn * 128) * 1024;

    auto STAGE = [&](int kt, int buf) {
        int k0 = kt * 128;
        char* Ad = As + buf * 16384;
        char* Bd = Bs + buf * 16384;
#pragma unroll
        for (int j = 0; j < 4; ++j) {
            int c = j * 4 + w;  // 1KB chunk (8 rows x 128B), wave-uniform LDS base
            gload_lds16(Ab + (size_t)(c * 8 + srow) * 1024 + k0 + scolb, Ad + c * 1024);
            gload_lds16(Wb + (size_t)(c * 8 + srow) * 1024 + k0 + scolb, Bd + c * 1024);
        }
    };

    STAGE(0, 0);
    __syncthreads();  // vmcnt(0) drain: buf0 ready
    for (int kt = 0; kt < 8; ++kt) {
        int cur = kt & 1;
        if (kt < 7) STAGE(kt + 1, cur ^ 1);  // prefetch rides under compute
        const char* Ar = As + cur * 16384;
        const char* Br = Bs + cur * 16384;
#pragma unroll
        for (int ks = 0; ks < 2; ++ks) {
            int kb = (ks * 64 + lh * 16) ^ key16;
            i32x4 af[4], bfr[4];
#pragma unroll
            for (int mi = 0; mi < 4; ++mi) af[mi] = *(const i32x4*)&Ar[(wr * 64 + mi * 16 + lr) * 128 + kb];
#pragma unroll
            for (int ni = 0; ni < 4; ++ni) bfr[ni] = *(const i32x4*)&Br[(wc * 64 + ni * 16 + lr) * 128 + kb];
#pragma unroll
            for (int mi = 0; mi < 4; ++mi)
#pragma unroll
                for (int ni = 0; ni < 4; ++ni) acc[mi][ni] = mfma_i8(af[mi], bfr[ni], acc[mi][ni]);
        }
        __syncthreads();  // drains prefetch + read/write fence
    }
#pragma unroll
    for (int mi = 0; mi < 4; ++mi) {
        int mbase = bm * 128 + wr * 64 + mi * 16 + lh * 4;
#pragma unroll
        for (int ni = 0; ni < 4; ++ni) {
            int n = bn * 128 + wc * 64 + ni * 16 + lr;
            if (MODE == 1) {
                int b = mbase >> 11, t0 = mbase & 2047;
                int h = n >> 6, d = n & 63;
                ushort4 st;
                st.x = f2bf((float)acc[mi][ni][0] * s_w / asc[mbase + 0]);
                st.y = f2bf((float)acc[mi][ni][1] * s_w / asc[mbase + 1]);
                st.z = f2bf((float)acc[mi][ni][2] * s_w / asc[mbase + 2]);
                st.w = f2bf((float)acc[mi][ni][3] * s_w / asc[mbase + 3]);
                *(ushort4*)&((unsigned short*)outp)[(size_t)(b * 16 + h) * 131072 + (size_t)d * 2048 + t0] = st;
            } else {
#pragma unroll
                for (int i = 0; i < 4; ++i) {
                    int m = mbase + i;
                    float val = (float)acc[mi][ni][i] * s_w / asc[m];
                    if (MODE == 0) {
                        int b = m >> 11, t = m & 2047, h = n >> 6, d = n & 63;
                        ((unsigned short*)outp)[(size_t)(b * 16 + h) * 131072 + (size_t)t * 64 + d] = f2bf(val);
                    } else {
                        ((float*)outp)[(size_t)m * 1024 + n] = val;
                    }
                }
            }
        }
    }
}

__device__ __forceinline__ float sw_from_part(const float* part) {
    float s = 0.f;
#pragma unroll
    for (int i = 0; i < 32; ++i) s += part[i];
    return fmaxf(s * (1.f / 1048576.f), 1e-5f);
}

// fused Q/K/V projection: blockIdx.z picks the gemm (0=q,1=k,2=v)
__global__ __launch_bounds__(256) void gemm_qkv(const signed char* __restrict__ abf,
                                                const float* __restrict__ ascale,
                                                const signed char* __restrict__ wq8,
                                                const float* __restrict__ part,
                                                unsigned short* __restrict__ qbf,
                                                unsigned short* __restrict__ kbf,
                                                unsigned short* __restrict__ vtb) {
    __shared__ alignas(16) char As[32768];  // 2 x 16KB dbuf
    __shared__ alignas(16) char Bs[32768];
    int z = blockIdx.z;
    const signed char* A = abf + (size_t)z * 4194304;
    const float* asc = ascale + z * 4096;
    const signed char* W = wq8 + (size_t)z * 1048576;
    float s_w = sw_from_part(part + z * 32);
    int bm = blockIdx.x, bn = blockIdx.y;
    if (z == 0) {
        gemm_core<0>(A, asc, W, s_w, qbf, bm, bn, As, Bs);
    } else if (z == 1) {
        gemm_core<0>(A, asc, W, s_w, kbf, bm, bn, As, Bs);
    } else {
        gemm_core<1>(A, asc, W, s_w, vtb, bm, bn, As, Bs);
    }
}

// output projection: f32 out
__global__ __launch_bounds__(256) void gemm_o(const signed char* __restrict__ A,
                                              const float* __restrict__ asc,
                                              const signed char* __restrict__ W,
                                              const float* __restrict__ part, float* __restrict__ outp) {
    __shared__ alignas(16) char As[32768];
    __shared__ alignas(16) char Bs[32768];
    float s_w = sw_from_part(part);
    gemm_core<2>(A, asc, W, s_w, outp, blockIdx.x, blockIdx.y, As, Bs);
}

// ---------------- flash attention (causal, 16 heads, D=64) ------------------
// 1 wave/block, 32 q-rows/wave (two 16-row fragments sharing one K/V stream).
// Swapped QK^T (S^T = mfma(K,Q)) -> per-lane in-register softmax in exp2
// domain. Diagonal-only causal mask; defer-max (T13, log2-THR=11); T5 setprio.
__global__ __launch_bounds__(64) void attn(const unsigned short* __restrict__ qb,
                                           const unsigned short* __restrict__ kb,
                                           const unsigned short* __restrict__ vt, float* __restrict__ y) {
    int blk = blockIdx.x;
    int bh = blk & 31;
    int c = 63 - (blk >> 5);  // 32-row chunk 0..63, heaviest first
    int q0 = c << 5;
    int l = threadIdx.x & 63;
    int lr = l & 15, lh = l >> 4;
    const unsigned short* qbase = qb + (size_t)bh * 131072;
    const unsigned short* kbase = kb + (size_t)bh * 131072;
    const unsigned short* vbase = vt + (size_t)bh * 131072;

    bf16x8 qf00 = *(const bf16x8*)&qbase[(size_t)(q0 + lr) * 64 + lh * 8];
    bf16x8 qf01 = *(const bf16x8*)&qbase[(size_t)(q0 + lr) * 64 + 32 + lh * 8];
    bf16x8 qf10 = *(const bf16x8*)&qbase[(size_t)(q0 + 16 + lr) * 64 + lh * 8];
    bf16x8 qf11 = *(const bf16x8*)&qbase[(size_t)(q0 + 16 + lr) * 64 + 32 + lh * 8];

    f32x4 o[4][2] = {};  // [dt][qt]
    const float ninf = -__builtin_inff();
    const float SC = 0.125f * 1.44269504f;  // 1/sqrt(64) * log2(e)
    float mreg0 = ninf, mreg1 = ninf;       // running max (log2 domain)
    float lreg0 = 0.f, lreg1 = 0.f;
    __shared__ alignas(16) unsigned short plds[2][16][40];

    int qrow0 = q0 + lr, qrow1 = q0 + 16 + lr;
    int ntiles = c + 1;

    auto LOADK = [&](int kv0, bf16x8* k) {
        k[0] = *(const bf16x8*)&kbase[(size_t)(kv0 + lr) * 64 + lh * 8];
        k[1] = *(const bf16x8*)&kbase[(size_t)(kv0 + lr) * 64 + 32 + lh * 8];
        k[2] = *(const bf16x8*)&kbase[(size_t)(kv0 + 16 + lr) * 64 + lh * 8];
        k[3] = *(const bf16x8*)&kbase[(size_t)(kv0 + 16 + lr) * 64 + 32 + lh * 8];
    };
    auto LOADV = [&](int kv0, bf16x8* v) {
        v[0] = *(const bf16x8*)&vbase[(size_t)(lr)*2048 + kv0 + lh * 8];
        v[1] = *(const bf16x8*)&vbase[(size_t)(16 + lr) * 2048 + kv0 + lh * 8];
        v[2] = *(const bf16x8*)&vbase[(size_t)(32 + lr) * 2048 + kv0 + lh * 8];
        v[3] = *(const bf16x8*)&vbase[(size_t)(48 + lr) * 2048 + kv0 + lh * 8];
    };
    auto PROCESS = [&](int t, bf16x8* k, bf16x8* v) {
        int kv0 = t << 5;
        __builtin_amdgcn_s_setprio(1);
        f32x4 s00 = {}, s01 = {}, s10 = {}, s11 = {};
        s00 = mfma16(k[0], qf00, s00);
        s00 = mfma16(k[1], qf01, s00);
        s01 = mfma16(k[2], qf00, s01);
        s01 = mfma16(k[3], qf01, s01);
        s10 = mfma16(k[0], qf10, s10);
        s10 = mfma16(k[1], qf11, s10);
        s11 = mfma16(k[2], qf10, s11);
        s11 = mfma16(k[3], qf11, s11);
        __builtin_amdgcn_s_setprio(0);
        float p0[8], p1[8];
        if (t == c) {
#pragma unroll
            for (int r = 0; r < 4; ++r) {
                int kva = kv0 + lh * 4 + r, kvb = kv0 + 16 + lh * 4 + r;
                p0[r]     = (kva <= qrow0) ? s00[r] * SC : ninf;
                p0[r + 4] = (kvb <= qrow0) ? s01[r] * SC : ninf;
                p1[r]     = (kva <= qrow1) ? s10[r] * SC : ninf;
                p1[r + 4] = (kvb <= qrow1) ? s11[r] * SC : ninf;
            }
        } else {
#pragma unroll
            for (int r = 0; r < 4; ++r) {
                p0[r] = s00[r] * SC;
                p0[r + 4] = s01[r] * SC;
                p1[r] = s10[r] * SC;
                p1[r + 4] = s11[r] * SC;
            }
        }
        float t0 = fmaxf(fmaxf(fmaxf(p0[0], p0[1]), fmaxf(p0[2], p0[3])),
                         fmaxf(fmaxf(p0[4], p0[5]), fmaxf(p0[6], p0[7])));
        float t1 = fmaxf(fmaxf(fmaxf(p1[0], p1[1]), fmaxf(p1[2], p1[3])),
                         fmaxf(fmaxf(p1[4], p1[5]), fmaxf(p1[6], p1[7])));
        t0 = fmaxf(t0, __shfl_xor(t0, 16));
        t0 = fmaxf(t0, __shfl_xor(t0, 32));
        t1 = fmaxf(t1, __shfl_xor(t1, 16));
        t1 = fmaxf(t1, __shfl_xor(t1, 32));
        if (__any((t0 > mreg0 + 11.f) || (t1 > mreg1 + 11.f))) {
            float mn0 = fmaxf(mreg0, t0), mn1 = fmaxf(mreg1, t1);
            float cc0 = exp2_fast(mreg0 - mn0), cc1 = exp2_fast(mreg1 - mn1);
            lreg0 *= cc0;
            lreg1 *= cc1;
            mreg0 = mn0;
            mreg1 = mn1;
#pragma unroll
            for (int dt = 0; dt < 4; ++dt)
#pragma unroll
                for (int r = 0; r < 4; ++r) {
                    o[dt][0][r] *= cc0;
                    o[dt][1][r] *= cc1;
                }
        }
        float ps0[8], ps1[8];
#pragma unroll
        for (int r = 0; r < 8; ++r) {
            ps0[r] = exp2_fast(p0[r] - mreg0);
            ps1[r] = exp2_fast(p1[r] - mreg1);
        }
        float sum0 = ((ps0[0] + ps0[1]) + (ps0[2] + ps0[3])) + ((ps0[4] + ps0[5]) + (ps0[6] + ps0[7]));
        float sum1 = ((ps1[0] + ps1[1]) + (ps1[2] + ps1[3])) + ((ps1[4] + ps1[5]) + (ps1[6] + ps1[7]));
        sum0 += __shfl_xor(sum0, 16);
        sum0 += __shfl_xor(sum0, 32);
        sum1 += __shfl_xor(sum1, 16);
        sum1 += __shfl_xor(sum1, 32);
        lreg0 += sum0;
        lreg1 += sum1;
        uint2 w0lo, w0hi, w1lo, w1hi;
        w0lo.x = cvtpk_bf16(ps0[0], ps0[1]);
        w0lo.y = cvtpk_bf16(ps0[2], ps0[3]);
        w0hi.x = cvtpk_bf16(ps0[4], ps0[5]);
        w0hi.y = cvtpk_bf16(ps0[6], ps0[7]);
        w1lo.x = cvtpk_bf16(ps1[0], ps1[1]);
        w1lo.y = cvtpk_bf16(ps1[2], ps1[3]);
        w1hi.x = cvtpk_bf16(ps1[4], ps1[5]);
        w1hi.y = cvtpk_bf16(ps1[6], ps1[7]);
        *(uint2*)&plds[0][lr][lh * 4] = w0lo;
        *(uint2*)&plds[0][lr][16 + lh * 4] = w0hi;
        *(uint2*)&plds[1][lr][lh * 4] = w1lo;
        *(uint2*)&plds[1][lr][16 + lh * 4] = w1hi;
        bf16x8 pf0 = *(const bf16x8*)&plds[0][lr][lh * 8];
        bf16x8 pf1 = *(const bf16x8*)&plds[1][lr][lh * 8];
        __builtin_amdgcn_s_setprio(1);
#pragma unroll
        for (int dt = 0; dt < 4; ++dt) {
            o[dt][0] = mfma16(v[dt], pf0, o[dt][0]);
            o[dt][1] = mfma16(v[dt], pf1, o[dt][1]);
        }
        __builtin_amdgcn_s_setprio(0);
    };

    bf16x8 kA[4], vA[4], kB[4], vB[4];
    LOADK(0, kA);
    LOADV(0, vA);
    int t = 0;
    while (true) {
        if (t + 1 < ntiles) { LOADK((t + 1) << 5, kB); LOADV((t + 1) << 5, vB); }
        PROCESS(t, kA, vA);
        if (++t >= ntiles) break;
        if (t + 1 < ntiles) { LOADK((t + 1) << 5, kA); LOADV((t + 1) << 5, vA); }
        PROCESS(t, kB, vB);
        if (++t >= ntiles) break;
    }

    int b = bh >> 4, h = bh & 15;
#pragma unroll
    for (int qt = 0; qt < 2; ++qt) {
        int qrow = (qt == 0) ? qrow0 : qrow1;
        float invl = 1.f / ((qt == 0) ? lreg0 : lreg1);
        float* yr = y + (size_t)(b * 2048 + qrow) * 1024 + h * 64;
#pragma unroll
        for (int dt = 0; dt < 4; ++dt) {
            float4 st;
            st.x = o[dt][qt][0] * invl;
            st.y = o[dt][qt][1] * invl;
            st.z = o[dt][qt][2] * invl;
            st.w = o[dt][qt][3] * invl;
            *(float4*)&yr[dt * 16 + lh * 4] = st;
        }
    }
}

extern "C" void kernel_launch(void* const* d_in, const int* in_sizes, int n_in,
                              void* d_out, int out_size, void* d_ws, size_t ws_size,
                              hipStream_t stream) {
    const float* x  = (const float*)d_in[0];
    const float* wq = (const float*)d_in[1];
    const float* wk = (const float*)d_in[2];
    const float* wv = (const float*)d_in[3];
    const float* wo = (const float*)d_in[4];
    const float* gq = (const float*)d_in[5];
    const float* gk = (const float*)d_in[6];
    const float* gv = (const float*)d_in[7];
    const float* go = (const float*)d_in[8];

    char* ws = (char*)d_ws;
    size_t off = 0;
    auto alloc = [&](size_t bytes) {
        size_t o = off;
        off += (bytes + 255) & ~(size_t)255;
        return o;
    };
    float* part = (float*)(ws + alloc(128 * 4));
    signed char* wq8 = (signed char*)(ws + alloc(4ull * 1048576));             // 4 x [1024][1024] i8
    signed char* abf = (signed char*)(ws + alloc(3ull * 4194304));             // 3 x [4096][1024] i8
    float* asc = (float*)(ws + alloc(3ull * 4096 * 4));
    unsigned short* qbf = (unsigned short*)(ws + alloc(4194304ull * 2));       // [BH][T][D] bf16
    unsigned short* kbf = (unsigned short*)(ws + alloc(4194304ull * 2));       // [BH][T][D] bf16
    unsigned short* vtb = (unsigned short*)(ws + alloc(4194304ull * 2));       // [BH][D][T] bf16
    float* ybuf = (float*)(ws + alloc(4194304ull * 4));                        // [B,T,C] f32
    signed char* ybf = (signed char*)(ws + alloc(4194304ull));                 // [M][C] i8
    float* ysc = (float*)(ws + alloc(4096 * 4));
    (void)ws_size; (void)in_sizes; (void)n_in; (void)out_size;

    wabssum<<<128, 256, 0, stream>>>(wq, wk, wv, wo, part);
    wquant<<<256, 256, 0, stream>>>(wq, wk, wv, wo, part, wq8);
    actquant<3><<<4096, 256, 0, stream>>>(x, gq, gk, gv, abf, asc);
    gemm_qkv<<<dim3(32, 8, 3), 256, 0, stream>>>(abf, asc, wq8, part, qbf, kbf, vtb);
    attn<<<2048, 64, 0, stream>>>(qbf, kbf, vtb, ybuf);
    actquant<1><<<4096, 256, 0, stream>>>(ybuf, go, go, go, ybf, ysc);
    gemm_o<<<dim3(32, 8), 256, 0, stream>>>(ybf, ysc, wq8 + 3ull * 1048576, part + 96, (float*)d_out);
}

// Round 10
// 144.470 us; speedup vs baseline: 4.1945x; 1.0009x over previous
//
#include <hip/hip_runtime.h>
#include <hip/hip_bf16.h>

// B=2, T=2048, C=1024, H=16, D=64, M=B*T=4096
// GEMMs: exact integer math via i8 MFMA (i32 accum, |dot| <= 130K exact).

typedef __attribute__((ext_vector_type(8))) short bf16x8;
typedef __attribute__((ext_vector_type(4))) float f32x4;
typedef __attribute__((ext_vector_type(4))) int i32x4;

__device__ __forceinline__ f32x4 mfma16(bf16x8 a, bf16x8 b, f32x4 c) {
    return __builtin_amdgcn_mfma_f32_16x16x32_bf16(a, b, c, 0, 0, 0);
}

__device__ __forceinline__ i32x4 mfma_i8(i32x4 a, i32x4 b, i32x4 c) {
    return __builtin_amdgcn_mfma_i32_16x16x64_i8(a, b, c, 0, 0, 0);
}

__device__ __forceinline__ unsigned short f2bf(float f) {
    unsigned int u = __float_as_uint(f);
    unsigned int r = (u + 0x7fffu + ((u >> 16) & 1u)) >> 16;
    return (unsigned short)r;
}

__device__ __forceinline__ unsigned int cvtpk_bf16(float lo, float hi) {
    unsigned int r;
    asm("v_cvt_pk_bf16_f32 %0, %1, %2" : "=v"(r) : "v"(lo), "v"(hi));
    return r;
}

__device__ __forceinline__ float exp2_fast(float x) {
    float r;
    asm("v_exp_f32 %0, %1" : "=v"(r) : "v"(x));
    return r;
}

__device__ __forceinline__ void gload_lds16(const void* g, void* l) {
    __builtin_amdgcn_global_load_lds((const __attribute__((address_space(1))) unsigned int*)g,
                                     (__attribute__((address_space(3))) unsigned int*)l, 16, 0, 0);
}

__device__ __forceinline__ int pack4i8(float a, float b, float c, float d) {
    unsigned int u = ((unsigned int)((int)a & 255)) | (((unsigned int)((int)b & 255)) << 8) |
                     (((unsigned int)((int)c & 255)) << 16) | (((unsigned int)((int)d & 255)) << 24);
    return (int)u;
}

__device__ __forceinline__ float wredsum(float v) {
#pragma unroll
    for (int o = 32; o > 0; o >>= 1) v += __shfl_xor(v, o);
    return v;
}
__device__ __forceinline__ float wredmax(float v) {
#pragma unroll
    for (int o = 32; o > 0; o >>= 1) v = fmaxf(v, __shfl_xor(v, o));
    return v;
}

// ---------------- weight absmean partials (deterministic two-pass) ----------
__global__ __launch_bounds__(256) void wabssum(const float* __restrict__ w0, const float* __restrict__ w1,
                                               const float* __restrict__ w2, const float* __restrict__ w3,
                                               float* __restrict__ part) {
    int widx = blockIdx.x >> 5, b = blockIdx.x & 31;
    const float* w = (widx == 0) ? w0 : (widx == 1) ? w1 : (widx == 2) ? w2 : w3;
    const float4* w4 = (const float4*)w;
    int tid = threadIdx.x;
    float s = 0.f;
    int base = b * 8192 + tid;
#pragma unroll
    for (int i = 0; i < 32; ++i) {
        float4 v = w4[base + i * 256];
        s += fabsf(v.x) + fabsf(v.y) + fabsf(v.z) + fabsf(v.w);
    }
    s = wredsum(s);
    __shared__ float red[4];
    int wid = tid >> 6, lid = tid & 63;
    if (lid == 0) red[wid] = s;
    __syncthreads();
    if (tid == 0) part[blockIdx.x] = red[0] + red[1] + red[2] + red[3];
}

// ---------------- ternary weight quant -> i8 {-1,0,1} -----------------------
__global__ __launch_bounds__(256) void wquant(const float* __restrict__ w0, const float* __restrict__ w1,
                                              const float* __restrict__ w2, const float* __restrict__ w3,
                                              const float* __restrict__ part, signed char* __restrict__ wq8) {
    int widx = blockIdx.x >> 6, b = blockIdx.x & 63;
    const float* w = (widx == 0) ? w0 : (widx == 1) ? w1 : (widx == 2) ? w2 : w3;
    float s = 0.f;
#pragma unroll
    for (int i = 0; i < 32; ++i) s += part[widx * 32 + i];
    s = fmaxf(s * (1.f / 1048576.f), 1e-5f);
    float inv = 1.f / s;
    const float4* w4 = (const float4*)w;
    int* dst = (int*)(wq8 + (size_t)widx * 1048576);
    int tid = threadIdx.x;
#pragma unroll
    for (int it = 0; it < 16; ++it) {
        int i4 = b * 4096 + it * 256 + tid;
        float4 v = w4[i4];
        float q0 = fminf(fmaxf(rintf(v.x * inv), -1.f), 1.f);
        float q1 = fminf(fmaxf(rintf(v.y * inv), -1.f), 1.f);
        float q2 = fminf(fmaxf(rintf(v.z * inv), -1.f), 1.f);
        float q3 = fminf(fmaxf(rintf(v.w * inv), -1.f), 1.f);
        dst[i4] = pack4i8(q0, q1, q2, q3);
    }
}

// ------------- fused rmsnorm + per-token absmax quant -> i8 (NP planes) -----
template <int NP>
__global__ __launch_bounds__(256) void actquant(const float* __restrict__ x, const float* __restrict__ g0,
                                                const float* __restrict__ g1, const float* __restrict__ g2,
                                                signed char* __restrict__ aq, float* __restrict__ ascale) {
    int m = blockIdx.x, tid = threadIdx.x;
    int wid = tid >> 6, lid = tid & 63;
    __shared__ float red[4];
    float4 xv = ((const float4*)(x + (size_t)m * 1024))[tid];
    float ss = xv.x * xv.x + xv.y * xv.y + xv.z * xv.z + xv.w * xv.w;
    ss = wredsum(ss);
    if (lid == 0) red[wid] = ss;
    __syncthreads();
    float rstd = rsqrtf((red[0] + red[1] + red[2] + red[3]) * (1.f / 1024.f) + 1e-6f);
    const float* gs[3] = {g0, g1, g2};
#pragma unroll
    for (int p = 0; p < NP; ++p) {
        float4 gv = ((const float4*)gs[p])[tid];
        float a0 = xv.x * gv.x * rstd, a1 = xv.y * gv.y * rstd;
        float a2 = xv.z * gv.z * rstd, a3 = xv.w * gv.w * rstd;
        float am = fmaxf(fmaxf(fabsf(a0), fabsf(a1)), fmaxf(fabsf(a2), fabsf(a3)));
        am = wredmax(am);
        __syncthreads();
        if (lid == 0) red[wid] = am;
        __syncthreads();
        float rm = fmaxf(fmaxf(red[0], red[1]), fmaxf(red[2], red[3]));
        float scale = 127.f / fmaxf(rm, 1e-5f);
        float q0 = fminf(fmaxf(rintf(a0 * scale), -128.f), 127.f);
        float q1 = fminf(fmaxf(rintf(a1 * scale), -128.f), 127.f);
        float q2 = fminf(fmaxf(rintf(a2 * scale), -128.f), 127.f);
        float q3 = fminf(fmaxf(rintf(a3 * scale), -128.f), 127.f);
        ((int*)(aq + (size_t)p * 4194304 + (size_t)m * 1024))[tid] = pack4i8(q0, q1, q2, q3);
        if (tid == 0) ascale[p * 4096 + m] = scale;
    }
}

// ------------- 128x128-tile i8 GEMM core (dbuf + XOR-swizzled LDS) ----------
// BK=128 i8, 256 thr = 2x2 waves, 4x4 16x16 frags/wave, K=1024 -> 8 steps.
// MODE 0: out bf16 [B,H,T,D]; MODE 1: out bf16 [BH,D,T]; MODE 2: out f32 [M,N]
template <int MODE>
__device__ __forceinline__ void gemm_core(const signed char* __restrict__ A,
                                          const float* __restrict__ asc,
                                          const signed char* __restrict__ W, float s_w,
                                          void* __restrict__ outp, int bm, int bn,
                                          char* As, char* Bs) {
    int tid = threadIdx.x;
    int w = tid >> 6, l = tid & 63;
    int wr = w >> 1, wc = w & 1;
    int lr = l & 15, lh = l >> 4;
    i32x4 acc[4][4] = {};
    int srow = l >> 3;                    // 0..7
    int scolb = (((l & 7) ^ srow)) * 16;  // pre-swizzled source col (bytes)
    int key16 = (lr & 7) * 16;            // read-side XOR key (bytes)
    const signed char* Ab = A + (size_t)(bm * 128) * 1024;
    const signed char* Wb = W + (size_t)(bn * 128) * 1024;

    auto STAGE = [&](int kt, int buf) {
        int k0 = kt * 128;
        char* Ad = As + buf * 16384;
        char* Bd = Bs + buf * 16384;
#pragma unroll
        for (int j = 0; j < 4; ++j) {
            int c = j * 4 + w;  // 1KB chunk (8 rows x 128B), wave-uniform LDS base
            gload_lds16(Ab + (size_t)(c * 8 + srow) * 1024 + k0 + scolb, Ad + c * 1024);
            gload_lds16(Wb + (size_t)(c * 8 + srow) * 1024 + k0 + scolb, Bd + c * 1024);
        }
    };

    STAGE(0, 0);
    __syncthreads();  // vmcnt(0) drain: buf0 ready
    for (int kt = 0; kt < 8; ++kt) {
        int cur = kt & 1;
        if (kt < 7) STAGE(kt + 1, cur ^ 1);  // prefetch rides under compute
        const char* Ar = As + cur * 16384;
        const char* Br = Bs + cur * 16384;
#pragma unroll
        for (int ks = 0; ks < 2; ++ks) {
            int kb = (ks * 64 + lh * 16) ^ key16;
            i32x4 af[4], bfr[4];
#pragma unroll
            for (int mi = 0; mi < 4; ++mi) af[mi] = *(const i32x4*)&Ar[(wr * 64 + mi * 16 + lr) * 128 + kb];
#pragma unroll
            for (int ni = 0; ni < 4; ++ni) bfr[ni] = *(const i32x4*)&Br[(wc * 64 + ni * 16 + lr) * 128 + kb];
#pragma unroll
            for (int mi = 0; mi < 4; ++mi)
#pragma unroll
                for (int ni = 0; ni < 4; ++ni) acc[mi][ni] = mfma_i8(af[mi], bfr[ni], acc[mi][ni]);
        }
        __syncthreads();  // drains prefetch + read/write fence
    }
#pragma unroll
    for (int mi = 0; mi < 4; ++mi) {
        int mbase = bm * 128 + wr * 64 + mi * 16 + lh * 4;
#pragma unroll
        for (int ni = 0; ni < 4; ++ni) {
            int n = bn * 128 + wc * 64 + ni * 16 + lr;
            if (MODE == 1) {
                int b = mbase >> 11, t0 = mbase & 2047;
                int h = n >> 6, d = n & 63;
                ushort4 st;
                st.x = f2bf((float)acc[mi][ni][0] * s_w / asc[mbase + 0]);
                st.y = f2bf((float)acc[mi][ni][1] * s_w / asc[mbase + 1]);
                st.z = f2bf((float)acc[mi][ni][2] * s_w / asc[mbase + 2]);
                st.w = f2bf((float)acc[mi][ni][3] * s_w / asc[mbase + 3]);
                *(ushort4*)&((unsigned short*)outp)[(size_t)(b * 16 + h) * 131072 + (size_t)d * 2048 + t0] = st;
            } else {
#pragma unroll
                for (int i = 0; i < 4; ++i) {
                    int m = mbase + i;
                    float val = (float)acc[mi][ni][i] * s_w / asc[m];
                    if (MODE == 0) {
                        int b = m >> 11, t = m & 2047, h = n >> 6, d = n & 63;
                        ((unsigned short*)outp)[(size_t)(b * 16 + h) * 131072 + (size_t)t * 64 + d] = f2bf(val);
                    } else {
                        ((float*)outp)[(size_t)m * 1024 + n] = val;
                    }
                }
            }
        }
    }
}

__device__ __forceinline__ float sw_from_part(const float* part) {
    float s = 0.f;
#pragma unroll
    for (int i = 0; i < 32; ++i) s += part[i];
    return fmaxf(s * (1.f / 1048576.f), 1e-5f);
}

// fused Q/K/V projection: blockIdx.z picks the gemm (0=q,1=k,2=v)
__global__ __launch_bounds__(256) void gemm_qkv(const signed char* __restrict__ abf,
                                                const float* __restrict__ ascale,
                                                const signed char* __restrict__ wq8,
                                                const float* __restrict__ part,
                                                unsigned short* __restrict__ qbf,
                                                unsigned short* __restrict__ kbf,
                                                unsigned short* __restrict__ vtb) {
    __shared__ alignas(16) char As[32768];  // 2 x 16KB dbuf
    __shared__ alignas(16) char Bs[32768];
    int z = blockIdx.z;
    const signed char* A = abf + (size_t)z * 4194304;
    const float* asc = ascale + z * 4096;
    const signed char* W = wq8 + (size_t)z * 1048576;
    float s_w = sw_from_part(part + z * 32);
    int bm = blockIdx.x, bn = blockIdx.y;
    if (z == 0) {
        gemm_core<0>(A, asc, W, s_w, qbf, bm, bn, As, Bs);
    } else if (z == 1) {
        gemm_core<0>(A, asc, W, s_w, kbf, bm, bn, As, Bs);
    } else {
        gemm_core<1>(A, asc, W, s_w, vtb, bm, bn, As, Bs);
    }
}

// output projection: f32 out
__global__ __launch_bounds__(256) void gemm_o(const signed char* __restrict__ A,
                                              const float* __restrict__ asc,
                                              const signed char* __restrict__ W,
                                              const float* __restrict__ part, float* __restrict__ outp) {
    __shared__ alignas(16) char As[32768];
    __shared__ alignas(16) char Bs[32768];
    float s_w = sw_from_part(part);
    gemm_core<2>(A, asc, W, s_w, outp, blockIdx.x, blockIdx.y, As, Bs);
}

// ---------------- flash attention (causal, 16 heads, D=64) ------------------
// 4 waves/block share one 32-q-row chunk; wave w processes kv-tiles t = w,
// w+4, ... <= c (disjoint kv -> critical path 64 -> 16 tiles) with private
// online-softmax state; block-end merge via LDS:
//   m* = max_w m_w, l* = sum l_w 2^(m_w-m*), O* = sum O_w 2^(m_w-m*).
// 2048 blocks on ~512 resident slots -> dynamic drain; heavy chunks first.
// Per-wave math identical to round-9 (swapped QK^T, exp2 softmax, diagonal
// mask on t==c, defer-max THR=11, setprio around MFMA clusters).
__global__ __launch_bounds__(256) void attn(const unsigned short* __restrict__ qb,
                                            const unsigned short* __restrict__ kb,
                                            const unsigned short* __restrict__ vt, float* __restrict__ y) {
    int blk = blockIdx.x;
    int bh = blk & 31;
    int c = 63 - (blk >> 5);  // 32-row chunk 0..63, heaviest first
    int q0 = c << 5;
    int w = threadIdx.x >> 6;
    int l = threadIdx.x & 63;
    int lr = l & 15, lh = l >> 4;
    const unsigned short* qbase = qb + (size_t)bh * 131072;
    const unsigned short* kbase = kb + (size_t)bh * 131072;
    const unsigned short* vbase = vt + (size_t)bh * 131072;

    bf16x8 qf00 = *(const bf16x8*)&qbase[(size_t)(q0 + lr) * 64 + lh * 8];
    bf16x8 qf01 = *(const bf16x8*)&qbase[(size_t)(q0 + lr) * 64 + 32 + lh * 8];
    bf16x8 qf10 = *(const bf16x8*)&qbase[(size_t)(q0 + 16 + lr) * 64 + lh * 8];
    bf16x8 qf11 = *(const bf16x8*)&qbase[(size_t)(q0 + 16 + lr) * 64 + 32 + lh * 8];

    f32x4 o[4][2] = {};  // [dt][qt]
    const float ninf = -__builtin_inff();
    const float SC = 0.125f * 1.44269504f;  // 1/sqrt(64) * log2(e)
    float mreg0 = ninf, mreg1 = ninf;       // running max (log2 domain)
    float lreg0 = 0.f, lreg1 = 0.f;
    __shared__ alignas(16) unsigned short plds[4][2][16][40];
    __shared__ alignas(16) float om[4][32][64];   // per-wave unnormalized O
    __shared__ float mlm[4][2][32];               // [w][0=m,1=l][row]

    int qrow0 = q0 + lr, qrow1 = q0 + 16 + lr;

    auto LOADK = [&](int kv0, bf16x8* k) {
        k[0] = *(const bf16x8*)&kbase[(size_t)(kv0 + lr) * 64 + lh * 8];
        k[1] = *(const bf16x8*)&kbase[(size_t)(kv0 + lr) * 64 + 32 + lh * 8];
        k[2] = *(const bf16x8*)&kbase[(size_t)(kv0 + 16 + lr) * 64 + lh * 8];
        k[3] = *(const bf16x8*)&kbase[(size_t)(kv0 + 16 + lr) * 64 + 32 + lh * 8];
    };
    auto LOADV = [&](int kv0, bf16x8* v) {
        v[0] = *(const bf16x8*)&vbase[(size_t)(lr)*2048 + kv0 + lh * 8];
        v[1] = *(const bf16x8*)&vbase[(size_t)(16 + lr) * 2048 + kv0 + lh * 8];
        v[2] = *(const bf16x8*)&vbase[(size_t)(32 + lr) * 2048 + kv0 + lh * 8];
        v[3] = *(const bf16x8*)&vbase[(size_t)(48 + lr) * 2048 + kv0 + lh * 8];
    };
    auto PROCESS = [&](int t, bf16x8* k, bf16x8* v) {
        int kv0 = t << 5;
        __builtin_amdgcn_s_setprio(1);
        f32x4 s00 = {}, s01 = {}, s10 = {}, s11 = {};
        s00 = mfma16(k[0], qf00, s00);
        s00 = mfma16(k[1], qf01, s00);
        s01 = mfma16(k[2], qf00, s01);
        s01 = mfma16(k[3], qf01, s01);
        s10 = mfma16(k[0], qf10, s10);
        s10 = mfma16(k[1], qf11, s10);
        s11 = mfma16(k[2], qf10, s11);
        s11 = mfma16(k[3], qf11, s11);
        __builtin_amdgcn_s_setprio(0);
        float p0[8], p1[8];
        if (t == c) {
#pragma unroll
            for (int r = 0; r < 4; ++r) {
                int kva = kv0 + lh * 4 + r, kvb = kv0 + 16 + lh * 4 + r;
                p0[r]     = (kva <= qrow0) ? s00[r] * SC : ninf;
                p0[r + 4] = (kvb <= qrow0) ? s01[r] * SC : ninf;
                p1[r]     = (kva <= qrow1) ? s10[r] * SC : ninf;
                p1[r + 4] = (kvb <= qrow1) ? s11[r] * SC : ninf;
            }
        } else {
#pragma unroll
            for (int r = 0; r < 4; ++r) {
                p0[r] = s00[r] * SC;
                p0[r + 4] = s01[r] * SC;
                p1[r] = s10[r] * SC;
                p1[r + 4] = s11[r] * SC;
            }
        }
        float t0 = fmaxf(fmaxf(fmaxf(p0[0], p0[1]), fmaxf(p0[2], p0[3])),
                         fmaxf(fmaxf(p0[4], p0[5]), fmaxf(p0[6], p0[7])));
        float t1 = fmaxf(fmaxf(fmaxf(p1[0], p1[1]), fmaxf(p1[2], p1[3])),
                         fmaxf(fmaxf(p1[4], p1[5]), fmaxf(p1[6], p1[7])));
        t0 = fmaxf(t0, __shfl_xor(t0, 16));
        t0 = fmaxf(t0, __shfl_xor(t0, 32));
        t1 = fmaxf(t1, __shfl_xor(t1, 16));
        t1 = fmaxf(t1, __shfl_xor(t1, 32));
        if (__any((t0 > mreg0 + 11.f) || (t1 > mreg1 + 11.f))) {
            float mn0 = fmaxf(mreg0, t0), mn1 = fmaxf(mreg1, t1);
            float cc0 = exp2_fast(mreg0 - mn0), cc1 = exp2_fast(mreg1 - mn1);
            lreg0 *= cc0;
            lreg1 *= cc1;
            mreg0 = mn0;
            mreg1 = mn1;
#pragma unroll
            for (int dt = 0; dt < 4; ++dt)
#pragma unroll
                for (int r = 0; r < 4; ++r) {
                    o[dt][0][r] *= cc0;
                    o[dt][1][r] *= cc1;
                }
        }
        float ps0[8], ps1[8];
#pragma unroll
        for (int r = 0; r < 8; ++r) {
            ps0[r] = exp2_fast(p0[r] - mreg0);
            ps1[r] = exp2_fast(p1[r] - mreg1);
        }
        float sum0 = ((ps0[0] + ps0[1]) + (ps0[2] + ps0[3])) + ((ps0[4] + ps0[5]) + (ps0[6] + ps0[7]));
        float sum1 = ((ps1[0] + ps1[1]) + (ps1[2] + ps1[3])) + ((ps1[4] + ps1[5]) + (ps1[6] + ps1[7]));
        sum0 += __shfl_xor(sum0, 16);
        sum0 += __shfl_xor(sum0, 32);
        sum1 += __shfl_xor(sum1, 16);
        sum1 += __shfl_xor(sum1, 32);
        lreg0 += sum0;
        lreg1 += sum1;
        uint2 w0lo, w0hi, w1lo, w1hi;
        w0lo.x = cvtpk_bf16(ps0[0], ps0[1]);
        w0lo.y = cvtpk_bf16(ps0[2], ps0[3]);
        w0hi.x = cvtpk_bf16(ps0[4], ps0[5]);
        w0hi.y = cvtpk_bf16(ps0[6], ps0[7]);
        w1lo.x = cvtpk_bf16(ps1[0], ps1[1]);
        w1lo.y = cvtpk_bf16(ps1[2], ps1[3]);
        w1hi.x = cvtpk_bf16(ps1[4], ps1[5]);
        w1hi.y = cvtpk_bf16(ps1[6], ps1[7]);
        *(uint2*)&plds[w][0][lr][lh * 4] = w0lo;
        *(uint2*)&plds[w][0][lr][16 + lh * 4] = w0hi;
        *(uint2*)&plds[w][1][lr][lh * 4] = w1lo;
        *(uint2*)&plds[w][1][lr][16 + lh * 4] = w1hi;
        bf16x8 pf0 = *(const bf16x8*)&plds[w][0][lr][lh * 8];
        bf16x8 pf1 = *(const bf16x8*)&plds[w][1][lr][lh * 8];
        __builtin_amdgcn_s_setprio(1);
#pragma unroll
        for (int dt = 0; dt < 4; ++dt) {
            o[dt][0] = mfma16(v[dt], pf0, o[dt][0]);
            o[dt][1] = mfma16(v[dt], pf1, o[dt][1]);
        }
        __builtin_amdgcn_s_setprio(0);
    };

    // wave w owns kv-tiles t = w, w+4, ... <= c (register double-buffered)
    int t = w;
    if (t <= c) {
        bf16x8 kA[4], vA[4], kB[4], vB[4];
        LOADK(t << 5, kA);
        LOADV(t << 5, vA);
        while (true) {
            if (t + 4 <= c) { LOADK((t + 4) << 5, kB); LOADV((t + 4) << 5, vB); }
            PROCESS(t, kA, vA);
            t += 4;
            if (t > c) break;
            if (t + 4 <= c) { LOADK((t + 4) << 5, kA); LOADV((t + 4) << 5, vA); }
            PROCESS(t, kB, vB);
            t += 4;
            if (t > c) break;
        }
    }

    // ---- block-end merge of 4 partial online-softmax states ----
#pragma unroll
    for (int dt = 0; dt < 4; ++dt) {
        *(float4*)&om[w][lr][dt * 16 + lh * 4] = *(float4*)&o[dt][0];
        *(float4*)&om[w][16 + lr][dt * 16 + lh * 4] = *(float4*)&o[dt][1];
    }
    if (lh == 0) {
        mlm[w][0][lr] = mreg0;
        mlm[w][1][lr] = lreg0;
        mlm[w][0][16 + lr] = mreg1;
        mlm[w][1][16 + lr] = lreg1;
    }
    __syncthreads();

    int tid = threadIdx.x;
    int row = tid >> 3;          // 0..31
    int d0 = (tid & 7) * 8;      // 0..56
    float m0 = mlm[0][0][row], m1 = mlm[1][0][row], m2 = mlm[2][0][row], m3 = mlm[3][0][row];
    float ms = fmaxf(fmaxf(m0, m1), fmaxf(m2, m3));
    float s0 = exp2_fast(m0 - ms), s1 = exp2_fast(m1 - ms);
    float s2 = exp2_fast(m2 - ms), s3 = exp2_fast(m3 - ms);
    float lt = mlm[0][1][row] * s0 + mlm[1][1][row] * s1 + mlm[2][1][row] * s2 + mlm[3][1][row] * s3;
    float invl = 1.f / lt;
    int b = bh >> 4, h = bh & 15;
    float* yr = y + (size_t)(b * 2048 + q0 + row) * 1024 + h * 64 + d0;
#pragma unroll
    for (int j = 0; j < 8; j += 4) {
        float4 v0 = *(float4*)&om[0][row][d0 + j];
        float4 v1 = *(float4*)&om[1][row][d0 + j];
        float4 v2 = *(float4*)&om[2][row][d0 + j];
        float4 v3 = *(float4*)&om[3][row][d0 + j];
        float4 st;
        st.x = (v0.x * s0 + v1.x * s1 + v2.x * s2 + v3.x * s3) * invl;
        st.y = (v0.y * s0 + v1.y * s1 + v2.y * s2 + v3.y * s3) * invl;
        st.z = (v0.z * s0 + v1.z * s1 + v2.z * s2 + v3.z * s3) * invl;
        st.w = (v0.w * s0 + v1.w * s1 + v2.w * s2 + v3.w * s3) * invl;
        *(float4*)&yr[j] = st;
    }
}

extern "C" void kernel_launch(void* const* d_in, const int* in_sizes, int n_in,
                              void* d_out, int out_size, void* d_ws, size_t ws_size,
                              hipStream_t stream) {
    const float* x  = (const float*)d_in[0];
    const float* wq = (const float*)d_in[1];
    const float* wk = (const float*)d_in[2];
    const float* wv = (const float*)d_in[3];
    const float* wo = (const float*)d_in[4];
    const float* gq = (const float*)d_in[5];
    const float* gk = (const float*)d_in[6];
    const float* gv = (const float*)d_in[7];
    const float* go = (const float*)d_in[8];

    char* ws = (char*)d_ws;
    size_t off = 0;
    auto alloc = [&](size_t bytes) {
        size_t o = off;
        off += (bytes + 255) & ~(size_t)255;
        return o;
    };
    float* part = (float*)(ws + alloc(128 * 4));
    signed char* wq8 = (signed char*)(ws + alloc(4ull * 1048576));             // 4 x [1024][1024] i8
    signed char* abf = (signed char*)(ws + alloc(3ull * 4194304));             // 3 x [4096][1024] i8
    float* asc = (float*)(ws + alloc(3ull * 4096 * 4));
    unsigned short* qbf = (unsigned short*)(ws + alloc(4194304ull * 2));       // [BH][T][D] bf16
    unsigned short* kbf = (unsigned short*)(ws + alloc(4194304ull * 2));       // [BH][T][D] bf16
    unsigned short* vtb = (unsigned short*)(ws + alloc(4194304ull * 2));       // [BH][D][T] bf16
    float* ybuf = (float*)(ws + alloc(4194304ull * 4));                        // [B,T,C] f32
    signed char* ybf = (signed char*)(ws + alloc(4194304ull));                 // [M][C] i8
    float* ysc = (float*)(ws + alloc(4096 * 4));
    (void)ws_size; (void)in_sizes; (void)n_in; (void)out_size;

    wabssum<<<128, 256, 0, stream>>>(wq, wk, wv, wo, part);
    wquant<<<256, 256, 0, stream>>>(wq, wk, wv, wo, part, wq8);
    actquant<3><<<4096, 256, 0, stream>>>(x, gq, gk, gv, abf, asc);
    gemm_qkv<<<dim3(32, 8, 3), 256, 0, stream>>>(abf, asc, wq8, part, qbf, kbf, vtb);
    attn<<<2048, 256, 0, stream>>>(qbf, kbf, vtb, ybuf);
    actquant<1><<<4096, 256, 0, stream>>>(ybuf, go, go, go, ybf, ysc);
    gemm_o<<<dim3(32, 8), 256, 0, stream>>>(ybf, ysc, wq8 + 3ull * 1048576, part + 96, (float*)d_out);
}